// Round 7
// baseline (343.837 us; speedup 1.0000x reference)
//
#include <hip/hip_runtime.h>

typedef unsigned short u16;
typedef float floatx4 __attribute__((ext_vector_type(4)));
typedef short shortx8 __attribute__((ext_vector_type(8)));

#define DIN 2048

__device__ __forceinline__ u16 f2bf(float f){
  unsigned u = __float_as_uint(f);
  u = (u + 0x7fffu + ((u>>16)&1u))>>16;
  return (u16)u;
}
__device__ __forceinline__ float sigf(float x){ return 1.f/(1.f+__expf(-x)); }
__device__ __forceinline__ float siluf(float x){ return x*sigf(x); }
__device__ __forceinline__ float softplusf(float x){ return fmaxf(x,0.f)+log1pf(__expf(-fabsf(x))); }

__device__ __forceinline__ void gld_lds16(const void* g, void* l){
  __builtin_amdgcn_global_load_lds((const __attribute__((address_space(1))) unsigned*)g,
                                   (__attribute__((address_space(3))) unsigned*)l, 16, 0, 0);
}

// ---------------- workspace layout (bytes) ----------------
#define OFF_WINP  0ull            // 4096x1024 bf16
#define OFF_WG1   8388608ull      // 1024x2048 bf16
#define OFF_WG2   12582912ull     // 2048x1024 bf16
#define OFF_WOP   16777216ull     // 1024x2048 bf16
#define OFF_XB    20971520ull     // 1024x1024 bf16
#define OFF_XIN   23068672ull     // 1024x2048 f32 (xin -> Hinit -> t1acc0)
#define OFF_SGATE 31457280ull     // 1024x2048 f32 silu(gate)
#define OFF_X1    39845888ull     // 512x2048 f32  (x1 -> t1acc1)
#define OFF_X2    44040192ull     // 256x2048 f32
#define OFF_XC0   46137344ull     // 1024x2048 f32 (first 4MB -> ctxb bf16; second 4MB -> ypacc1)
#define OFF_XC1   54525952ull     // 512x2048 f32  (xc1 -> t1b bf16)
#define OFF_XC2   58720256ull     // 256x2048 f32
#define OFF_FUSED 60817408ull     // 1024x2048 f32 fused
#define OFF_G3O   69206016ull     // 1024x2048 bf16 g3o
#define OFF_Y0    75497472ull     // 1024x2048 f32 (pre-scan: PS summaries span Y0..Y2)
#define OFF_Y1    83886080ull     // 512x2048 f32  (y1 -> ypacc0)
#define OFF_Y2    88080384ull     // 256x2048 f32
#define OFF_P0    90177536ull     // 1024x32 f32
#define OFF_P1    90308608ull     // 512x32 f32
#define OFF_P2    90374144ull     // 256x32 f32  (end 90406912 ~ 86.2 MiB)
// aliases
#define OFF_CTXB  OFF_XC0
#define OFF_T1B   OFF_XC1
#define OFF_PS    OFF_Y0
#define OFF_HINIT OFF_XIN
#define OFF_T1A0  OFF_XIN
#define OFF_T1A1  OFF_X1
#define OFF_YPA0  OFF_Y1
#define OFF_YPA1  (OFF_XC0 + 4194304ull)

// ---------------- f32 -> bf16 conversion (5 segments, 4 elems/thread) ----------------
__global__ __launch_bounds__(256) void cvt_kernel(
    const float* __restrict__ s0, u16* __restrict__ d0,
    const float* __restrict__ s1, u16* __restrict__ d1,
    const float* __restrict__ s2, u16* __restrict__ d2,
    const float* __restrict__ s3, u16* __restrict__ d3,
    const float* __restrict__ s4, u16* __restrict__ d4)
{
  int i = (blockIdx.x*256 + threadIdx.x)*4;
  const float* s; u16* d;
  if      (i <  4194304){ s=s0; d=d0; }
  else if (i <  6291456){ s=s1; d=d1; i -=  4194304; }
  else if (i <  8388608){ s=s2; d=d2; i -=  6291456; }
  else if (i < 10485760){ s=s3; d=d3; i -=  8388608; }
  else                  { s=s4; d=d4; i -= 10485760; }
  const float4 v = *(const float4*)(s + i);
  ushort4 o; o.x = f2bf(v.x); o.y = f2bf(v.y); o.z = f2bf(v.z); o.w = f2bf(v.w);
  *(ushort4*)(d + i) = o;
}

// ---------------- MFMA bt-GEMM (R5-vetted inner loop): BK=32, dbuf, no swizzle ------
// C[m][n] = sum_k A[m][k]*B[n][k] (A,B bf16, row stride K)
// MODE 0: n<2048 -> f32 x_in (out_f) + fused downsample (ex0=x1, ex1=x2);
//         n>=2048 -> f32 silu(gate) (out_f2)
// MODE 2: bf16 sigmoid(acc)*ex0f[idx]*ex1f[idx] -> out_b
// MODE 4: raw f32 partial -> (blockIdx.z ? out_f2 : out_f);  kStart = z*Ks
template<int MODE, int BM>
__global__ __launch_bounds__(256) void gemm_bt(
    const u16* __restrict__ A, const u16* __restrict__ B,
    int N, int K, int Ks,
    float* __restrict__ out_f, float* __restrict__ out_f2, u16* __restrict__ out_b,
    const float* __restrict__ ex0f, const float* __restrict__ ex1f,
    float* __restrict__ ex0, float* __restrict__ ex1)
{
  constexpr int NI = BM/32;        // 16x16 tiles per wave dim
  constexpr int IP = BM/64;        // gld_lds16 issues per matrix per thread
  __shared__ u16 smA[2][BM*32];
  __shared__ u16 smB[2][BM*32];
  const int tid  = threadIdx.x;
  const int m0   = blockIdx.y * BM;
  const int n0   = blockIdx.x * BM;
  const int wv   = tid >> 6;
  const int lane = tid & 63;
  const int mw   = (wv >> 1) * (BM/2);
  const int nw   = (wv & 1) * (BM/2);
  const int quad = lane >> 4;
  const int l16  = lane & 15;
  const int srow = tid >> 2;
  const int scol = (tid & 3) * 8;

  floatx4 acc[NI][NI];
#pragma unroll
  for (int i=0;i<NI;i++)
#pragma unroll
    for (int j=0;j<NI;j++) acc[i][j] = (floatx4)0.f;

  const int kStart = blockIdx.z * Ks;
  const int kEnd   = kStart + Ks;

  auto stage = [&](int buf, int k0){
#pragma unroll
    for (int p=0;p<IP;p++){
      gld_lds16(A + (size_t)(m0 + p*64 + srow)*K + k0 + scol, &smA[buf][p*2048 + wv*512]);
      gld_lds16(B + (size_t)(n0 + p*64 + srow)*K + k0 + scol, &smB[buf][p*2048 + wv*512]);
    }
  };

  stage(0, kStart);
  int cur = 0;
  for (int k0 = kStart; k0 < kEnd; k0 += 32) {
    __syncthreads();                       // staging of cur done; prev reads of cur^1 done
    if (k0 + 32 < kEnd) stage(cur^1, k0+32);
    shortx8 af[NI], bfr[NI];
#pragma unroll
    for (int i=0;i<NI;i++){
      af[i]  = *(const shortx8*)&smA[cur][(mw + i*16 + l16)*32 + quad*8];
      bfr[i] = *(const shortx8*)&smB[cur][(nw + i*16 + l16)*32 + quad*8];
    }
#pragma unroll
    for (int i=0;i<NI;i++)
#pragma unroll
      for (int j=0;j<NI;j++)
        acc[i][j] = __builtin_amdgcn_mfma_f32_16x16x32_bf16(af[i], bfr[j], acc[i][j], 0, 0, 0);
    cur ^= 1;
  }

#pragma unroll
  for (int i=0;i<NI;i++){
    const int mb = m0 + mw + i*16 + quad*4;   // 4 consecutive rows per lane, mb%4==0
#pragma unroll
    for (int j=0;j<NI;j++){
      const int n = n0 + nw + j*16 + l16;
      const floatx4 v4 = acc[i][j];
      if (MODE == 0){
        if (n < 2048){
#pragma unroll
          for (int r=0;r<4;r++) out_f[(size_t)(mb+r)*2048 + n] = v4[r];
          ex0[(size_t)(mb>>1)*2048 + n]       = 0.5f*(v4[0]+v4[1]);
          ex0[(size_t)((mb>>1)+1)*2048 + n]   = 0.5f*(v4[2]+v4[3]);
          ex1[(size_t)(mb>>2)*2048 + n]       = 0.25f*(v4[0]+v4[1]+v4[2]+v4[3]);
        } else {
#pragma unroll
          for (int r=0;r<4;r++) out_f2[(size_t)(mb+r)*2048 + (n-2048)] = siluf(v4[r]);
        }
      } else if (MODE == 2){
#pragma unroll
        for (int r=0;r<4;r++){
          const size_t idx = (size_t)(mb+r)*N + n;
          out_b[idx] = f2bf(sigf(v4[r]) * ex0f[idx] * ex1f[idx]);
        }
      } else {
        float* dst = blockIdx.z ? out_f2 : out_f;
#pragma unroll
        for (int r=0;r<4;r++) dst[(size_t)(mb+r)*N + n] = v4[r];
      }
    }
  }
}

// ---------------- G2 combine: t1 = silu(acc0+acc1) -> bf16 ----------------
__global__ __launch_bounds__(256) void g2_epi(const float* __restrict__ a,
    const float* __restrict__ b, u16* __restrict__ o){
  const int i = (blockIdx.x*256 + threadIdx.x)*4;
  const float4 va = *(const float4*)(a+i);
  const float4 vb = *(const float4*)(b+i);
  ushort4 r;
  r.x = f2bf(siluf(va.x+vb.x)); r.y = f2bf(siluf(va.y+vb.y));
  r.z = f2bf(siluf(va.z+vb.z)); r.w = f2bf(siluf(va.w+vb.w));
  *(ushort4*)(o+i) = r;
}

// ---------------- causal depthwise conv (K=4) + silu, all scales ----------------
__global__ __launch_bounds__(256) void conv_kernel(const float* __restrict__ xin,
    const float* __restrict__ x1, const float* __restrict__ x2,
    const float* __restrict__ cw, const float* __restrict__ cb,
    float* __restrict__ xc0, float* __restrict__ xc1, float* __restrict__ xc2){
  const int idx = blockIdx.x*256 + threadIdx.x;
  const float* xs; float* xc; int s, local;
  if (idx < 1024*DIN)              { s=0; local=idx;             xs=xin; xc=xc0; }
  else if (idx < (1024+512)*DIN)   { s=1; local=idx-1024*DIN;    xs=x1;  xc=xc1; }
  else                             { s=2; local=idx-1536*DIN;    xs=x2;  xc=xc2; }
  const int t = local >> 11, d = local & 2047;
  const float* w = cw + ((size_t)(s*DIN) + d)*4;
  float acc = cb[s*DIN + d];
#pragma unroll
  for (int j=0;j<4;j++){
    const int tt = t - 3 + j;
    if (tt >= 0) acc += w[j] * xs[(size_t)tt*DIN + d];
  }
  xc[local] = siluf(acc);
}

// ---------------- xproj: block per t, xc row staged in LDS ----------------
__global__ __launch_bounds__(256) void xproj_kernel(const float* __restrict__ xc0,
    const float* __restrict__ xc1, const float* __restrict__ xc2,
    const float* __restrict__ xw,
    float* __restrict__ p0, float* __restrict__ p1, float* __restrict__ p2){
  __shared__ float srow[DIN];
  const int b = blockIdx.x;
  const float* xc; float* proj; int s, t;
  if (b < 1024)      { s=0; t=b;       xc=xc0; proj=p0; }
  else if (b < 1536) { s=1; t=b-1024;  xc=xc1; proj=p1; }
  else               { s=2; t=b-1536;  xc=xc2; proj=p2; }
  const float* xr = xc + (size_t)t*DIN;
  const int tid = threadIdx.x;
#pragma unroll
  for (int q=0;q<2;q++){
    const int k = (q*256 + tid)*4;
    *(float4*)&srow[k] = *(const float4*)&xr[k];
  }
  __syncthreads();
  const int i = tid >> 3;
  const int j = tid & 7;
  const float* w = xw + ((size_t)s*32 + i)*DIN;
  float acc = 0.f;
#pragma unroll 8
  for (int c=0;c<256;c++){
    const int k = j + 8*c;
    acc += srow[k]*w[k];
  }
  acc += __shfl_xor(acc,1); acc += __shfl_xor(acc,2); acc += __shfl_xor(acc,4);
  if (j == 0) proj[t*32 + i] = acc;
}

// ---------------- chunked scan, phase 1 (dtproj fused) ----------------
__global__ __launch_bounds__(256) void scan_p1(
    const float* __restrict__ xc0, const float* __restrict__ xc1, const float* __restrict__ xc2,
    const float* __restrict__ p0,  const float* __restrict__ p1,  const float* __restrict__ p2,
    const float* __restrict__ dtw, const float* __restrict__ dtb,
    float2* __restrict__ PS)
{
  __shared__ float sproj[32*32];
  int b = blockIdx.x;
  const float *xc, *proj; int base, s;
  if (b < 256)      { xc=xc0; proj=p0; base=0;  s=0; }
  else if (b < 384) { b-=256; xc=xc1; proj=p1; base=32; s=1; }
  else              { b-=384; xc=xc2; proj=p2; base=48; s=2; }
  const int chunk = b >> 3;
  const int d     = (b & 7)*256 + threadIdx.x;
  const int t0    = chunk*32;
  {
    const int k = threadIdx.x*4;
    *(float4*)&sproj[k] = *(const float4*)&proj[t0*32 + k];
  }
  __syncthreads();

  float wreg[16];
  const float* wr = dtw + ((size_t)(s*DIN) + d)*16;
#pragma unroll
  for (int n=0;n<16;n++) wreg[n] = wr[n];
  const float bias = dtb[s*DIN + d];

  float H[16], P[16];
#pragma unroll
  for (int n=0;n<16;n++){ H[n]=0.f; P[n]=1.f; }
  const float* xcp = xc + (size_t)t0*DIN + d;
  float xcn = xcp[0];
  for (int tt=0; tt<32; tt++){
    const float xcv = xcn;
    if (tt < 31) xcn = xcp[(size_t)(tt+1)*DIN];
    const float* Bp = &sproj[tt*32];
    float bs = bias;
#pragma unroll
    for (int n=0;n<16;n++) bs += Bp[n]*wreg[n];
    const float dtv = softplusf(softplusf(bs));
    const float e = __expf(-dtv);          // dt >= ln2 -> e <= 0.5
    const float c = dtv*xcv;
    float ep = e;
#pragma unroll
    for (int n=0;n<16;n++){
      const float dA  = fmaxf(ep, 1e-38f);
      const float dBx = fmaxf(c*Bp[n], 1e-38f);
      H[n] = dA*H[n] + dBx;
      P[n] *= dA;
      ep *= e;
    }
  }
  float2* o = PS + ((size_t)(base+chunk)*2048 + d)*16;
#pragma unroll
  for (int n=0;n<16;n++){ float2 v; v.x=P[n]; v.y=H[n]; o[n]=v; }
}

// ---------------- combine ----------------
__global__ __launch_bounds__(256) void scan_combine(const float2* __restrict__ PS,
                                                    float* __restrict__ Hinit){
  int id = blockIdx.x*256 + threadIdx.x;
  int base, C;
  if (id < 32768)      { base=0;  C=32; }
  else if (id < 65536) { id-=32768; base=32; C=16; }
  else                 { id-=65536; base=48; C=8;  }
  const size_t off = (size_t)base*32768 + id;
  const float2* ps = PS + off;
  float* hi = Hinit + off;
  float H = 0.f;
  for (int c=0;c<C;c++){
    hi[(size_t)c*32768] = H;
    const float2 v = ps[(size_t)c*32768];
    H = v.x*H + v.y;
  }
}

// ---------------- chunked scan, phase 2 (dtproj fused) ----------------
__global__ __launch_bounds__(256) void scan_p2(
    const float* __restrict__ xc0, const float* __restrict__ xc1, const float* __restrict__ xc2,
    const float* __restrict__ p0,  const float* __restrict__ p1,  const float* __restrict__ p2,
    const float* __restrict__ dtw, const float* __restrict__ dtb,
    const float* __restrict__ Hinit, const float* __restrict__ Dp_all,
    float* __restrict__ y0, float* __restrict__ y1, float* __restrict__ y2)
{
  __shared__ float sproj[32*32];
  int b = blockIdx.x;
  const float *xc, *proj; float* y; int base, s;
  if (b < 256)      { xc=xc0; proj=p0; y=y0; base=0;  s=0; }
  else if (b < 384) { b-=256; xc=xc1; proj=p1; y=y1; base=32; s=1; }
  else              { b-=384; xc=xc2; proj=p2; y=y2; base=48; s=2; }
  const int chunk = b >> 3;
  const int d     = (b & 7)*256 + threadIdx.x;
  const int t0    = chunk*32;
  {
    const int k = threadIdx.x*4;
    *(float4*)&sproj[k] = *(const float4*)&proj[t0*32 + k];
  }
  __syncthreads();

  float wreg[16];
  const float* wr = dtw + ((size_t)(s*DIN) + d)*16;
#pragma unroll
  for (int n=0;n<16;n++) wreg[n] = wr[n];
  const float bias = dtb[s*DIN + d];

  float H[16];
  const float* hi = Hinit + ((size_t)(base+chunk)*2048 + d)*16;
#pragma unroll
  for (int n=0;n<16;n++) H[n] = hi[n];
  const float Dv = Dp_all[s*DIN + d];
  const float* xcp = xc + (size_t)t0*DIN + d;
  float* yp = y + (size_t)t0*DIN + d;
  float xcn = xcp[0];
  for (int tt=0; tt<32; tt++){
    const float xcv = xcn;
    if (tt < 31) xcn = xcp[(size_t)(tt+1)*DIN];
    const float* Bp = &sproj[tt*32];
    float bs = bias;
#pragma unroll
    for (int n=0;n<16;n++) bs += Bp[n]*wreg[n];
    const float dtv = softplusf(softplusf(bs));
    const float e = __expf(-dtv);
    const float c = dtv*xcv;
    float ep = e;
    float pacc = 0.f;
#pragma unroll
    for (int n=0;n<16;n++){
      const float dA  = fmaxf(ep, 1e-38f);
      const float dBx = fmaxf(c*Bp[n], 1e-38f);
      H[n] = dA*H[n] + dBx;
      pacc += Bp[16+n]*H[n];
      ep *= e;
    }
    yp[(size_t)tt*DIN] = pacc + Dv*xcv;
  }
}

// ---------------- upsample + fuse + ctx ----------------
__device__ __forceinline__ float ups_read(const float* __restrict__ ys, int Tin, int t, int d){
  const float scale = (float)Tin * (1.f/1024.f);
  float pos = ((float)t + 0.5f)*scale - 0.5f;
  pos = fminf(fmaxf(pos, 0.f), (float)(Tin-1));
  const int lo = (int)floorf(pos);
  const float w = pos - (float)lo;
  const int hi = min(lo+1, Tin-1);
  return ys[(size_t)lo*DIN + d]*(1.f-w) + ys[(size_t)hi*DIN + d]*w;
}

__global__ __launch_bounds__(256) void fuse_kernel(const float* __restrict__ y0,
    const float* __restrict__ y1, const float* __restrict__ y2,
    const float* __restrict__ sw, u16* __restrict__ ctxb, float* __restrict__ fused){
  const int idx = blockIdx.x*256 + threadIdx.x;
  const int t = idx >> 11, d = idx & 2047;
  const float w0r = sw[0], w1r = sw[1], w2r = sw[2];
  const float mx = fmaxf(w0r, fmaxf(w1r, w2r));
  float e0 = __expf(w0r-mx), e1 = __expf(w1r-mx), e2 = __expf(w2r-mx);
  const float inv = 1.f/(e0+e1+e2);
  e0 *= inv; e1 *= inv; e2 *= inv;
  const float o0 = y0[idx];
  const float o1 = ups_read(y1, 512, t, d);
  const float o2 = ups_read(y2, 256, t, d);
  fused[idx] = e0*o0 + e1*o1 + e2*o2;
  ctxb[idx]  = f2bf((o0+o1+o2)*(1.f/3.f));
}

// ---------------- LayerNorm (reads split-K partials + residual) ----------------
__global__ __launch_bounds__(256) void ln_kernel(const float* __restrict__ ya,
    const float* __restrict__ yb, const float* __restrict__ xr,
    const float* __restrict__ g, const float* __restrict__ b, float* __restrict__ out){
  __shared__ float red[4];
  const int t = blockIdx.x;
  const size_t ro = (size_t)t*1024;
  float v[4];
  float s = 0.f;
#pragma unroll
  for (int i=0;i<4;i++){
    const int c = threadIdx.x + i*256;
    v[i] = ya[ro+c] + yb[ro+c] + xr[ro+c];
    s += v[i];
  }
  s += __shfl_xor(s,1); s += __shfl_xor(s,2); s += __shfl_xor(s,4);
  s += __shfl_xor(s,8); s += __shfl_xor(s,16); s += __shfl_xor(s,32);
  if ((threadIdx.x & 63) == 0) red[threadIdx.x>>6] = s;
  __syncthreads();
  const float mu = (red[0]+red[1]+red[2]+red[3]) * (1.f/1024.f);
  __syncthreads();
  float q = 0.f;
#pragma unroll
  for (int i=0;i<4;i++){ const float dd = v[i]-mu; q += dd*dd; }
  q += __shfl_xor(q,1); q += __shfl_xor(q,2); q += __shfl_xor(q,4);
  q += __shfl_xor(q,8); q += __shfl_xor(q,16); q += __shfl_xor(q,32);
  if ((threadIdx.x & 63) == 0) red[threadIdx.x>>6] = q;
  __syncthreads();
  const float rstd = rsqrtf((red[0]+red[1]+red[2]+red[3]) * (1.f/1024.f) + 1e-5f);
#pragma unroll
  for (int i=0;i<4;i++){
    const int c = threadIdx.x + i*256;
    out[ro + c] = (v[i]-mu)*rstd*g[c] + b[c];
  }
}

extern "C" void kernel_launch(void* const* d_in, const int* in_sizes, int n_in,
                              void* d_out, int out_size, void* d_ws, size_t ws_size,
                              hipStream_t stream) {
  const float* x     = (const float*)d_in[0];
  const float* inpw  = (const float*)d_in[1];
  const float* convw = (const float*)d_in[2];
  const float* convb = (const float*)d_in[3];
  const float* xpw   = (const float*)d_in[4];
  const float* dtw   = (const float*)d_in[5];
  const float* dtb   = (const float*)d_in[6];
  const float* Dp    = (const float*)d_in[7];
  const float* sw    = (const float*)d_in[8];
  const float* gw1   = (const float*)d_in[9];
  const float* gw2   = (const float*)d_in[10];
  const float* opw   = (const float*)d_in[11];
  const float* lng   = (const float*)d_in[12];
  const float* lnb   = (const float*)d_in[13];
  float* out = (float*)d_out;

  char* ws = (char*)d_ws;
  u16*    wInp  = (u16*)   (ws + OFF_WINP);
  u16*    wG1   = (u16*)   (ws + OFF_WG1);
  u16*    wG2   = (u16*)   (ws + OFF_WG2);
  u16*    wOp   = (u16*)   (ws + OFF_WOP);
  u16*    xb    = (u16*)   (ws + OFF_XB);
  float*  xin   = (float*) (ws + OFF_XIN);
  float*  sgate = (float*) (ws + OFF_SGATE);
  float*  x1    = (float*) (ws + OFF_X1);
  float*  x2    = (float*) (ws + OFF_X2);
  float*  xc0   = (float*) (ws + OFF_XC0);
  float*  xc1   = (float*) (ws + OFF_XC1);
  float*  xc2   = (float*) (ws + OFF_XC2);
  float*  y0    = (float*) (ws + OFF_Y0);
  float*  y1    = (float*) (ws + OFF_Y1);
  float*  y2    = (float*) (ws + OFF_Y2);
  float*  p0    = (float*) (ws + OFF_P0);
  float*  p1    = (float*) (ws + OFF_P1);
  float*  p2    = (float*) (ws + OFF_P2);
  float2* PS    = (float2*)(ws + OFF_PS);
  float*  Hinit = (float*) (ws + OFF_HINIT);
  u16*    ctxb  = (u16*)   (ws + OFF_CTXB);
  u16*    t1b   = (u16*)   (ws + OFF_T1B);
  float*  fused = (float*) (ws + OFF_FUSED);
  u16*    g3o   = (u16*)   (ws + OFF_G3O);
  float*  t1a0  = (float*) (ws + OFF_T1A0);
  float*  t1a1  = (float*) (ws + OFF_T1A1);
  float*  ypa0  = (float*) (ws + OFF_YPA0);
  float*  ypa1  = (float*) (ws + OFF_YPA1);

  // convert f32 -> bf16: big GEMM weights + x
  cvt_kernel<<<11264, 256, 0, stream>>>(inpw, wInp, gw1, wG1, gw2, wG2, opw, wOp, x, xb);
  // G1: xz = x @ in_proj_w^T -> x_in (f32) + downsampled x1,x2 + silu(gate)  [1024 blocks]
  gemm_bt<0,64><<<dim3(64, 16, 1), 256, 0, stream>>>(xb, wInp, 4096, 1024, 1024,
                                                     xin, sgate, nullptr, nullptr, nullptr, x1, x2);
  // conv + silu (all scales)
  conv_kernel<<<(1792*DIN)/256, 256, 0, stream>>>(xin, x1, x2, convw, convb, xc0, xc1, xc2);
  // xproj (block per t, LDS-staged xc row)
  xproj_kernel<<<1792, 256, 0, stream>>>(xc0, xc1, xc2, xpw, p0, p1, p2);
  // chunked SSM scan (dtproj fused into p1/p2)
  scan_p1<<<448, 256, 0, stream>>>(xc0, xc1, xc2, p0, p1, p2, dtw, dtb, PS);
  scan_combine<<<384, 256, 0, stream>>>(PS, Hinit);
  scan_p2<<<448, 256, 0, stream>>>(xc0, xc1, xc2, p0, p1, p2, dtw, dtb,
                                   Hinit, Dp, y0, y1, y2);
  // upsample + fuse + ctx
  fuse_kernel<<<(1024*DIN)/256, 256, 0, stream>>>(y0, y1, y2, sw, ctxb, fused);
  // G2: ctx @ gate_w1^T  split-K=2 -> partials  [512 blocks]
  gemm_bt<4,64><<<dim3(16, 16, 2), 256, 0, stream>>>(ctxb, wG1, 1024, 2048, 1024,
                                                     t1a0, t1a1, nullptr, nullptr, nullptr, nullptr, nullptr);
  g2_epi<<<1024, 256, 0, stream>>>(t1a0, t1a1, t1b);
  // G3: g3o = sigmoid(t1 @ gate_w2^T) * fused * sgate  [512 blocks]
  gemm_bt<2,64><<<dim3(32, 16, 1), 256, 0, stream>>>(t1b, wG2, 2048, 1024, 1024,
                                                     nullptr, nullptr, g3o, fused, sgate, nullptr, nullptr);
  // G4: g3o @ out_proj_w^T  split-K=2 -> partials  [512 blocks]
  gemm_bt<4,64><<<dim3(16, 16, 2), 256, 0, stream>>>(g3o, wOp, 1024, 2048, 1024,
                                                     ypa0, ypa1, nullptr, nullptr, nullptr, nullptr, nullptr);
  // LayerNorm (sums partials + residual) -> f32 out
  ln_kernel<<<1024, 256, 0, stream>>>(ypa0, ypa1, x, lng, lnb, out);
}

// Round 8
// 336.911 us; speedup vs baseline: 1.0206x; 1.0206x over previous
//
#include <hip/hip_runtime.h>

typedef unsigned short u16;
typedef float floatx4 __attribute__((ext_vector_type(4)));
typedef short shortx8 __attribute__((ext_vector_type(8)));

#define DIN 2048

__device__ __forceinline__ u16 f2bf(float f){
  unsigned u = __float_as_uint(f);
  u = (u + 0x7fffu + ((u>>16)&1u))>>16;
  return (u16)u;
}
__device__ __forceinline__ float sigf(float x){ return 1.f/(1.f+__expf(-x)); }
__device__ __forceinline__ float siluf(float x){ return x*sigf(x); }
__device__ __forceinline__ float softplusf(float x){ return fmaxf(x,0.f)+log1pf(__expf(-fabsf(x))); }

__device__ __forceinline__ void gld_lds16(const void* g, void* l){
  __builtin_amdgcn_global_load_lds((const __attribute__((address_space(1))) unsigned*)g,
                                   (__attribute__((address_space(3))) unsigned*)l, 16, 0, 0);
}

// ---------------- workspace layout (bytes) ----------------
#define OFF_WINP  0ull            // 4096x1024 bf16
#define OFF_WG1   8388608ull      // 1024x2048 bf16
#define OFF_WG2   12582912ull     // 2048x1024 bf16
#define OFF_WOP   16777216ull     // 1024x2048 bf16
#define OFF_XB    20971520ull     // 1024x1024 bf16
#define OFF_XIN   23068672ull     // 1024x2048 f32 (xin -> Hinit -> t1acc0)
#define OFF_SGATE 31457280ull     // 1024x2048 f32 silu(gate)
#define OFF_X1    39845888ull     // 512x2048 f32  (x1 -> t1acc1)
#define OFF_X2    44040192ull     // 256x2048 f32
#define OFF_XC0   46137344ull     // 1024x2048 f32 (first 4MB -> ctxb bf16; second 4MB -> ypacc1)
#define OFF_XC1   54525952ull     // 512x2048 f32  (xc1 -> t1b bf16)
#define OFF_XC2   58720256ull     // 256x2048 f32
#define OFF_FUSED 60817408ull     // 1024x2048 f32 (pre-fuse: dt0) -> fused
#define OFF_G3O   69206016ull     // (pre-fuse: dt1 4MB + dt2 2MB) -> g3o bf16 4MB
#define OFF_Y0    75497472ull     // 1024x2048 f32 (pre-scan: PS summaries span Y0..Y2)
#define OFF_Y1    83886080ull     // 512x2048 f32  (y1 -> ypacc0)
#define OFF_Y2    88080384ull     // 256x2048 f32
#define OFF_P0    90177536ull     // 1024x32 f32
#define OFF_P1    90308608ull     // 512x32 f32
#define OFF_P2    90374144ull     // 256x32 f32  (end 90406912 ~ 86.2 MiB)
// aliases
#define OFF_CTXB  OFF_XC0
#define OFF_T1B   OFF_XC1
#define OFF_PS    OFF_Y0
#define OFF_HINIT OFF_XIN
#define OFF_T1A0  OFF_XIN
#define OFF_T1A1  OFF_X1
#define OFF_YPA0  OFF_Y1
#define OFF_YPA1  (OFF_XC0 + 4194304ull)
#define OFF_DT0   OFF_FUSED                  // 8 MB (dead until fuse_kernel)
#define OFF_DT1   OFF_G3O                    // 4 MB (dead until G3)
#define OFF_DT2   (OFF_G3O + 4194304ull)     // 2 MB (ends exactly at Y0)

// ---------------- f32 -> bf16 conversion (5 segments, 4 elems/thread) ----------------
__global__ __launch_bounds__(256) void cvt_kernel(
    const float* __restrict__ s0, u16* __restrict__ d0,
    const float* __restrict__ s1, u16* __restrict__ d1,
    const float* __restrict__ s2, u16* __restrict__ d2,
    const float* __restrict__ s3, u16* __restrict__ d3,
    const float* __restrict__ s4, u16* __restrict__ d4)
{
  int i = (blockIdx.x*256 + threadIdx.x)*4;
  const float* s; u16* d;
  if      (i <  4194304){ s=s0; d=d0; }
  else if (i <  6291456){ s=s1; d=d1; i -=  4194304; }
  else if (i <  8388608){ s=s2; d=d2; i -=  6291456; }
  else if (i < 10485760){ s=s3; d=d3; i -=  8388608; }
  else                  { s=s4; d=d4; i -= 10485760; }
  const float4 v = *(const float4*)(s + i);
  ushort4 o; o.x = f2bf(v.x); o.y = f2bf(v.y); o.z = f2bf(v.z); o.w = f2bf(v.w);
  *(ushort4*)(d + i) = o;
}

// ---------------- MFMA bt-GEMM (R5/R7-vetted inner loop): BK=32, dbuf ----------
// MODE 0: n<2048 -> f32 x_in (out_f) + fused downsample (ex0=x1, ex1=x2);
//         n>=2048 -> f32 silu(gate) (out_f2)
// MODE 2: bf16 sigmoid(acc)*ex0f[idx]*ex1f[idx] -> out_b
// MODE 4: raw f32 partial -> (blockIdx.z ? out_f2 : out_f);  kStart = z*Ks
template<int MODE, int BM>
__global__ __launch_bounds__(256) void gemm_bt(
    const u16* __restrict__ A, const u16* __restrict__ B,
    int N, int K, int Ks,
    float* __restrict__ out_f, float* __restrict__ out_f2, u16* __restrict__ out_b,
    const float* __restrict__ ex0f, const float* __restrict__ ex1f,
    float* __restrict__ ex0, float* __restrict__ ex1)
{
  constexpr int NI = BM/32;
  constexpr int IP = BM/64;
  __shared__ u16 smA[2][BM*32];
  __shared__ u16 smB[2][BM*32];
  const int tid  = threadIdx.x;
  const int m0   = blockIdx.y * BM;
  const int n0   = blockIdx.x * BM;
  const int wv   = tid >> 6;
  const int lane = tid & 63;
  const int mw   = (wv >> 1) * (BM/2);
  const int nw   = (wv & 1) * (BM/2);
  const int quad = lane >> 4;
  const int l16  = lane & 15;
  const int srow = tid >> 2;
  const int scol = (tid & 3) * 8;

  floatx4 acc[NI][NI];
#pragma unroll
  for (int i=0;i<NI;i++)
#pragma unroll
    for (int j=0;j<NI;j++) acc[i][j] = (floatx4)0.f;

  const int kStart = blockIdx.z * Ks;
  const int kEnd   = kStart + Ks;

  auto stage = [&](int buf, int k0){
#pragma unroll
    for (int p=0;p<IP;p++){
      gld_lds16(A + (size_t)(m0 + p*64 + srow)*K + k0 + scol, &smA[buf][p*2048 + wv*512]);
      gld_lds16(B + (size_t)(n0 + p*64 + srow)*K + k0 + scol, &smB[buf][p*2048 + wv*512]);
    }
  };

  stage(0, kStart);
  int cur = 0;
  for (int k0 = kStart; k0 < kEnd; k0 += 32) {
    __syncthreads();
    if (k0 + 32 < kEnd) stage(cur^1, k0+32);
    shortx8 af[NI], bfr[NI];
#pragma unroll
    for (int i=0;i<NI;i++){
      af[i]  = *(const shortx8*)&smA[cur][(mw + i*16 + l16)*32 + quad*8];
      bfr[i] = *(const shortx8*)&smB[cur][(nw + i*16 + l16)*32 + quad*8];
    }
#pragma unroll
    for (int i=0;i<NI;i++)
#pragma unroll
      for (int j=0;j<NI;j++)
        acc[i][j] = __builtin_amdgcn_mfma_f32_16x16x32_bf16(af[i], bfr[j], acc[i][j], 0, 0, 0);
    cur ^= 1;
  }

#pragma unroll
  for (int i=0;i<NI;i++){
    const int mb = m0 + mw + i*16 + quad*4;
#pragma unroll
    for (int j=0;j<NI;j++){
      const int n = n0 + nw + j*16 + l16;
      const floatx4 v4 = acc[i][j];
      if (MODE == 0){
        if (n < 2048){
#pragma unroll
          for (int r=0;r<4;r++) out_f[(size_t)(mb+r)*2048 + n] = v4[r];
          ex0[(size_t)(mb>>1)*2048 + n]       = 0.5f*(v4[0]+v4[1]);
          ex0[(size_t)((mb>>1)+1)*2048 + n]   = 0.5f*(v4[2]+v4[3]);
          ex1[(size_t)(mb>>2)*2048 + n]       = 0.25f*(v4[0]+v4[1]+v4[2]+v4[3]);
        } else {
#pragma unroll
          for (int r=0;r<4;r++) out_f2[(size_t)(mb+r)*2048 + (n-2048)] = siluf(v4[r]);
        }
      } else if (MODE == 2){
#pragma unroll
        for (int r=0;r<4;r++){
          const size_t idx = (size_t)(mb+r)*N + n;
          out_b[idx] = f2bf(sigf(v4[r]) * ex0f[idx] * ex1f[idx]);
        }
      } else {
        float* dst = blockIdx.z ? out_f2 : out_f;
#pragma unroll
        for (int r=0;r<4;r++) dst[(size_t)(mb+r)*N + n] = v4[r];
      }
    }
  }
}

// ---------------- G2 combine: t1 = silu(acc0+acc1) -> bf16 ----------------
__global__ __launch_bounds__(256) void g2_epi(const float* __restrict__ a,
    const float* __restrict__ b, u16* __restrict__ o){
  const int i = (blockIdx.x*256 + threadIdx.x)*4;
  const float4 va = *(const float4*)(a+i);
  const float4 vb = *(const float4*)(b+i);
  ushort4 r;
  r.x = f2bf(siluf(va.x+vb.x)); r.y = f2bf(siluf(va.y+vb.y));
  r.z = f2bf(siluf(va.z+vb.z)); r.w = f2bf(siluf(va.w+vb.w));
  *(ushort4*)(o+i) = r;
}

// ---------------- causal depthwise conv (K=4) + silu, all scales ----------------
__global__ __launch_bounds__(256) void conv_kernel(const float* __restrict__ xin,
    const float* __restrict__ x1, const float* __restrict__ x2,
    const float* __restrict__ cw, const float* __restrict__ cb,
    float* __restrict__ xc0, float* __restrict__ xc1, float* __restrict__ xc2){
  const int idx = blockIdx.x*256 + threadIdx.x;
  const float* xs; float* xc; int s, local;
  if (idx < 1024*DIN)              { s=0; local=idx;             xs=xin; xc=xc0; }
  else if (idx < (1024+512)*DIN)   { s=1; local=idx-1024*DIN;    xs=x1;  xc=xc1; }
  else                             { s=2; local=idx-1536*DIN;    xs=x2;  xc=xc2; }
  const int t = local >> 11, d = local & 2047;
  const float* w = cw + ((size_t)(s*DIN) + d)*4;
  float acc = cb[s*DIN + d];
#pragma unroll
  for (int j=0;j<4;j++){
    const int tt = t - 3 + j;
    if (tt >= 0) acc += w[j] * xs[(size_t)tt*DIN + d];
  }
  xc[local] = siluf(acc);
}

// ---------------- xproj: block per t, xc row staged in LDS ----------------
__global__ __launch_bounds__(256) void xproj_kernel(const float* __restrict__ xc0,
    const float* __restrict__ xc1, const float* __restrict__ xc2,
    const float* __restrict__ xw,
    float* __restrict__ p0, float* __restrict__ p1, float* __restrict__ p2){
  __shared__ float srow[DIN];
  const int b = blockIdx.x;
  const float* xc; float* proj; int s, t;
  if (b < 1024)      { s=0; t=b;       xc=xc0; proj=p0; }
  else if (b < 1536) { s=1; t=b-1024;  xc=xc1; proj=p1; }
  else               { s=2; t=b-1536;  xc=xc2; proj=p2; }
  const float* xr = xc + (size_t)t*DIN;
  const int tid = threadIdx.x;
#pragma unroll
  for (int q=0;q<2;q++){
    const int k = (q*256 + tid)*4;
    *(float4*)&srow[k] = *(const float4*)&xr[k];
  }
  __syncthreads();
  const int i = tid >> 3;
  const int j = tid & 7;
  const float* w = xw + ((size_t)s*32 + i)*DIN;
  float acc = 0.f;
#pragma unroll 8
  for (int c=0;c<256;c++){
    const int k = j + 8*c;
    acc += srow[k]*w[k];
  }
  acc += __shfl_xor(acc,1); acc += __shfl_xor(acc,2); acc += __shfl_xor(acc,4);
  if (j == 0) proj[t*32 + i] = acc;
}

// ---------------- chunked scan, phase 1: pair-split states, dt store, closed-form P --
// blocks: s0 512, s1 256, s2 128 = 896.  thread: d = dblk*128 + tid/2, half = tid&1.
__global__ __launch_bounds__(256) void scan_p1(
    const float* __restrict__ xc0, const float* __restrict__ xc1, const float* __restrict__ xc2,
    const float* __restrict__ p0,  const float* __restrict__ p1,  const float* __restrict__ p2,
    const float* __restrict__ dtw, const float* __restrict__ dtb,
    float* __restrict__ dt0, float* __restrict__ dt1, float* __restrict__ dt2,
    float2* __restrict__ PS)
{
  __shared__ float sproj[32*32];
  int b = blockIdx.x;
  const float *xc, *proj; float* dto; int base, s;
  if (b < 512)      { xc=xc0; proj=p0; dto=dt0; base=0;  s=0; }
  else if (b < 768) { b-=512; xc=xc1; proj=p1; dto=dt1; base=32; s=1; }
  else              { b-=768; xc=xc2; proj=p2; dto=dt2; base=48; s=2; }
  const int chunk = b >> 4;
  const int tid   = threadIdx.x;
  const int d     = (b & 15)*128 + (tid >> 1);
  const int half  = tid & 1;
  const int n0    = half*8;
  const int t0    = chunk*32;
  { const int k = tid*4; *(float4*)&sproj[k] = *(const float4*)&proj[t0*32 + k]; }
  __syncthreads();

  float wreg[8];
  const float* wr = dtw + ((size_t)(s*DIN) + d)*16 + n0;
#pragma unroll
  for (int k=0;k<8;k++) wreg[k] = wr[k];
  const float bias = dtb[s*DIN + d];

  float H[8];
#pragma unroll
  for (int k=0;k<8;k++) H[k] = 0.f;
  float S = 0.f;
  const float* xcp = xc + (size_t)t0*DIN + d;
  float* dtp = dto + (size_t)t0*DIN + d;
  for (int tt=0; tt<32; tt++){
    const float xcv = xcp[(size_t)tt*DIN];
    const float* Bp = &sproj[tt*32];
    float bs = 0.f;
#pragma unroll
    for (int k=0;k<8;k++) bs += Bp[n0+k]*wreg[k];
    bs += __shfl_xor(bs, 1);
    const float dtv = softplusf(softplusf(bs + bias));
    if (half == 0) dtp[(size_t)tt*DIN] = dtv;
    S += dtv;
    const float e = __expf(-dtv);          // dt > ln2 -> e < 0.5
    const float e2 = e*e, e4 = e2*e2, e8 = e4*e4;
    float ep = half ? e8*e : e;            // e^(n0+1)
    const float c = dtv*xcv;
#pragma unroll
    for (int k=0;k<8;k++){
      const float dA  = fmaxf(ep, 1e-38f);
      const float dBx = fmaxf(c*Bp[n0+k], 1e-38f);
      H[k] = dA*H[k] + dBx;
      ep *= e;
    }
  }
  // chunk product P[n] = exp(-(n+1)*S)  (clamp-divergence only in denormal range)
  const float q = __expf(-S);
  const float q2 = q*q, q4 = q2*q2, q8 = q4*q4;
  float qp = half ? q8*q : q;
  float2* o = PS + ((size_t)(base+chunk)*2048 + d)*16 + n0;
#pragma unroll
  for (int k=0;k<8;k++){ float2 v; v.x = qp; v.y = H[k]; o[k] = v; qp *= q; }
}

// ---------------- combine (unchanged; 56 chunk summaries) ----------------
__global__ __launch_bounds__(256) void scan_combine(const float2* __restrict__ PS,
                                                    float* __restrict__ Hinit){
  int id = blockIdx.x*256 + threadIdx.x;
  int base, C;
  if (id < 32768)      { base=0;  C=32; }
  else if (id < 65536) { id-=32768; base=32; C=16; }
  else                 { id-=65536; base=48; C=8;  }
  const size_t off = (size_t)base*32768 + id;
  const float2* ps = PS + off;
  float* hi = Hinit + off;
  float H = 0.f;
  for (int c=0;c<C;c++){
    hi[(size_t)c*32768] = H;
    const float2 v = ps[(size_t)c*32768];
    H = v.x*H + v.y;
  }
}

// ---------------- chunked scan, phase 2: pair-split, dt preloaded ----------------
__global__ __launch_bounds__(256) void scan_p2(
    const float* __restrict__ xc0, const float* __restrict__ xc1, const float* __restrict__ xc2,
    const float* __restrict__ p0,  const float* __restrict__ p1,  const float* __restrict__ p2,
    const float* __restrict__ dt0, const float* __restrict__ dt1, const float* __restrict__ dt2,
    const float* __restrict__ Hinit, const float* __restrict__ Dp_all,
    float* __restrict__ y0, float* __restrict__ y1, float* __restrict__ y2)
{
  __shared__ float sproj[32*32];
  int b = blockIdx.x;
  const float *xc, *proj, *dti; float* y; int base, s;
  if (b < 512)      { xc=xc0; proj=p0; dti=dt0; y=y0; base=0;  s=0; }
  else if (b < 768) { b-=512; xc=xc1; proj=p1; dti=dt1; y=y1; base=32; s=1; }
  else              { b-=768; xc=xc2; proj=p2; dti=dt2; y=y2; base=48; s=2; }
  const int chunk = b >> 4;
  const int tid   = threadIdx.x;
  const int d     = (b & 15)*128 + (tid >> 1);
  const int half  = tid & 1;
  const int n0    = half*8;
  const int t0    = chunk*32;
  { const int k = tid*4; *(float4*)&sproj[k] = *(const float4*)&proj[t0*32 + k]; }
  __syncthreads();

  float H[8];
  const float* hi = Hinit + ((size_t)(base+chunk)*2048 + d)*16 + n0;
#pragma unroll
  for (int k=0;k<8;k++) H[k] = hi[k];
  const float Dv = Dp_all[s*DIN + d];
  const float* xcp = xc + (size_t)t0*DIN + d;
  const float* dtp = dti + (size_t)t0*DIN + d;
  float* yp = y + (size_t)t0*DIN + d;
  for (int tt=0; tt<32; tt++){
    const float xcv = xcp[(size_t)tt*DIN];
    const float dtv = dtp[(size_t)tt*DIN];
    const float* Bp = &sproj[tt*32];
    const float e = __expf(-dtv);
    const float e2 = e*e, e4 = e2*e2, e8 = e4*e4;
    float ep = half ? e8*e : e;
    const float c = dtv*xcv;
    float pacc = 0.f;
#pragma unroll
    for (int k=0;k<8;k++){
      const float dA  = fmaxf(ep, 1e-38f);
      const float dBx = fmaxf(c*Bp[n0+k], 1e-38f);
      H[k] = dA*H[k] + dBx;
      pacc += Bp[16+n0+k]*H[k];
      ep *= e;
    }
    pacc += __shfl_xor(pacc, 1);
    if (half == 0) yp[(size_t)tt*DIN] = pacc + Dv*xcv;
  }
}

// ---------------- upsample + fuse + ctx ----------------
__device__ __forceinline__ float ups_read(const float* __restrict__ ys, int Tin, int t, int d){
  const float scale = (float)Tin * (1.f/1024.f);
  float pos = ((float)t + 0.5f)*scale - 0.5f;
  pos = fminf(fmaxf(pos, 0.f), (float)(Tin-1));
  const int lo = (int)floorf(pos);
  const float w = pos - (float)lo;
  const int hi = min(lo+1, Tin-1);
  return ys[(size_t)lo*DIN + d]*(1.f-w) + ys[(size_t)hi*DIN + d]*w;
}

__global__ __launch_bounds__(256) void fuse_kernel(const float* __restrict__ y0,
    const float* __restrict__ y1, const float* __restrict__ y2,
    const float* __restrict__ sw, u16* __restrict__ ctxb, float* __restrict__ fused){
  const int idx = blockIdx.x*256 + threadIdx.x;
  const int t = idx >> 11, d = idx & 2047;
  const float w0r = sw[0], w1r = sw[1], w2r = sw[2];
  const float mx = fmaxf(w0r, fmaxf(w1r, w2r));
  float e0 = __expf(w0r-mx), e1 = __expf(w1r-mx), e2 = __expf(w2r-mx);
  const float inv = 1.f/(e0+e1+e2);
  e0 *= inv; e1 *= inv; e2 *= inv;
  const float o0 = y0[idx];
  const float o1 = ups_read(y1, 512, t, d);
  const float o2 = ups_read(y2, 256, t, d);
  fused[idx] = e0*o0 + e1*o1 + e2*o2;
  ctxb[idx]  = f2bf((o0+o1+o2)*(1.f/3.f));
}

// ---------------- LayerNorm (reads split-K partials + residual) ----------------
__global__ __launch_bounds__(256) void ln_kernel(const float* __restrict__ ya,
    const float* __restrict__ yb, const float* __restrict__ xr,
    const float* __restrict__ g, const float* __restrict__ b, float* __restrict__ out){
  __shared__ float red[4];
  const int t = blockIdx.x;
  const size_t ro = (size_t)t*1024;
  float v[4];
  float s = 0.f;
#pragma unroll
  for (int i=0;i<4;i++){
    const int c = threadIdx.x + i*256;
    v[i] = ya[ro+c] + yb[ro+c] + xr[ro+c];
    s += v[i];
  }
  s += __shfl_xor(s,1); s += __shfl_xor(s,2); s += __shfl_xor(s,4);
  s += __shfl_xor(s,8); s += __shfl_xor(s,16); s += __shfl_xor(s,32);
  if ((threadIdx.x & 63) == 0) red[threadIdx.x>>6] = s;
  __syncthreads();
  const float mu = (red[0]+red[1]+red[2]+red[3]) * (1.f/1024.f);
  __syncthreads();
  float q = 0.f;
#pragma unroll
  for (int i=0;i<4;i++){ const float dd = v[i]-mu; q += dd*dd; }
  q += __shfl_xor(q,1); q += __shfl_xor(q,2); q += __shfl_xor(q,4);
  q += __shfl_xor(q,8); q += __shfl_xor(q,16); q += __shfl_xor(q,32);
  if ((threadIdx.x & 63) == 0) red[threadIdx.x>>6] = q;
  __syncthreads();
  const float rstd = rsqrtf((red[0]+red[1]+red[2]+red[3]) * (1.f/1024.f) + 1e-5f);
#pragma unroll
  for (int i=0;i<4;i++){
    const int c = threadIdx.x + i*256;
    out[ro + c] = (v[i]-mu)*rstd*g[c] + b[c];
  }
}

extern "C" void kernel_launch(void* const* d_in, const int* in_sizes, int n_in,
                              void* d_out, int out_size, void* d_ws, size_t ws_size,
                              hipStream_t stream) {
  const float* x     = (const float*)d_in[0];
  const float* inpw  = (const float*)d_in[1];
  const float* convw = (const float*)d_in[2];
  const float* convb = (const float*)d_in[3];
  const float* xpw   = (const float*)d_in[4];
  const float* dtw   = (const float*)d_in[5];
  const float* dtb   = (const float*)d_in[6];
  const float* Dp    = (const float*)d_in[7];
  const float* sw    = (const float*)d_in[8];
  const float* gw1   = (const float*)d_in[9];
  const float* gw2   = (const float*)d_in[10];
  const float* opw   = (const float*)d_in[11];
  const float* lng   = (const float*)d_in[12];
  const float* lnb   = (const float*)d_in[13];
  float* out = (float*)d_out;

  char* ws = (char*)d_ws;
  u16*    wInp  = (u16*)   (ws + OFF_WINP);
  u16*    wG1   = (u16*)   (ws + OFF_WG1);
  u16*    wG2   = (u16*)   (ws + OFF_WG2);
  u16*    wOp   = (u16*)   (ws + OFF_WOP);
  u16*    xb    = (u16*)   (ws + OFF_XB);
  float*  xin   = (float*) (ws + OFF_XIN);
  float*  sgate = (float*) (ws + OFF_SGATE);
  float*  x1    = (float*) (ws + OFF_X1);
  float*  x2    = (float*) (ws + OFF_X2);
  float*  xc0   = (float*) (ws + OFF_XC0);
  float*  xc1   = (float*) (ws + OFF_XC1);
  float*  xc2   = (float*) (ws + OFF_XC2);
  float*  dt0   = (float*) (ws + OFF_DT0);
  float*  dt1   = (float*) (ws + OFF_DT1);
  float*  dt2   = (float*) (ws + OFF_DT2);
  float*  y0    = (float*) (ws + OFF_Y0);
  float*  y1    = (float*) (ws + OFF_Y1);
  float*  y2    = (float*) (ws + OFF_Y2);
  float*  p0    = (float*) (ws + OFF_P0);
  float*  p1    = (float*) (ws + OFF_P1);
  float*  p2    = (float*) (ws + OFF_P2);
  float2* PS    = (float2*)(ws + OFF_PS);
  float*  Hinit = (float*) (ws + OFF_HINIT);
  u16*    ctxb  = (u16*)   (ws + OFF_CTXB);
  u16*    t1b   = (u16*)   (ws + OFF_T1B);
  float*  fused = (float*) (ws + OFF_FUSED);
  u16*    g3o   = (u16*)   (ws + OFF_G3O);
  float*  t1a0  = (float*) (ws + OFF_T1A0);
  float*  t1a1  = (float*) (ws + OFF_T1A1);
  float*  ypa0  = (float*) (ws + OFF_YPA0);
  float*  ypa1  = (float*) (ws + OFF_YPA1);

  // convert f32 -> bf16: big GEMM weights + x
  cvt_kernel<<<11264, 256, 0, stream>>>(inpw, wInp, gw1, wG1, gw2, wG2, opw, wOp, x, xb);
  // G1: xz = x @ in_proj_w^T -> x_in (f32) + downsampled x1,x2 + silu(gate)  [1024 blocks]
  gemm_bt<0,64><<<dim3(64, 16, 1), 256, 0, stream>>>(xb, wInp, 4096, 1024, 1024,
                                                     xin, sgate, nullptr, nullptr, nullptr, x1, x2);
  // conv + silu (all scales)
  conv_kernel<<<(1792*DIN)/256, 256, 0, stream>>>(xin, x1, x2, convw, convb, xc0, xc1, xc2);
  // xproj (block per t, LDS-staged xc row)
  xproj_kernel<<<1792, 256, 0, stream>>>(xc0, xc1, xc2, xpw, p0, p1, p2);
  // chunked SSM scan (pair-split states; dt computed in p1, reused in p2)
  scan_p1<<<896, 256, 0, stream>>>(xc0, xc1, xc2, p0, p1, p2, dtw, dtb,
                                   dt0, dt1, dt2, PS);
  scan_combine<<<384, 256, 0, stream>>>(PS, Hinit);
  scan_p2<<<896, 256, 0, stream>>>(xc0, xc1, xc2, p0, p1, p2, dt0, dt1, dt2,
                                   Hinit, Dp, y0, y1, y2);
  // upsample + fuse + ctx  (fused overwrites dt0 — dead; ctxb over xc0)
  fuse_kernel<<<(1024*DIN)/256, 256, 0, stream>>>(y0, y1, y2, sw, ctxb, fused);
  // G2: ctx @ gate_w1^T  split-K=2 -> partials  [512 blocks]
  gemm_bt<4,64><<<dim3(16, 16, 2), 256, 0, stream>>>(ctxb, wG1, 1024, 2048, 1024,
                                                     t1a0, t1a1, nullptr, nullptr, nullptr, nullptr, nullptr);
  g2_epi<<<1024, 256, 0, stream>>>(t1a0, t1a1, t1b);
  // G3: g3o = sigmoid(t1 @ gate_w2^T) * fused * sgate  [512 blocks; g3o over dt1 — dead]
  gemm_bt<2,64><<<dim3(32, 16, 1), 256, 0, stream>>>(t1b, wG2, 2048, 1024, 1024,
                                                     nullptr, nullptr, g3o, fused, sgate, nullptr, nullptr);
  // G4: g3o @ out_proj_w^T  split-K=2 -> partials  [512 blocks]
  gemm_bt<4,64><<<dim3(16, 16, 2), 256, 0, stream>>>(g3o, wOp, 1024, 2048, 1024,
                                                     ypa0, ypa1, nullptr, nullptr, nullptr, nullptr, nullptr);
  // LayerNorm (sums partials + residual) -> f32 out
  ln_kernel<<<1024, 256, 0, stream>>>(ypa0, ypa1, x, lng, lnb, out);
}

// Round 9
// 302.878 us; speedup vs baseline: 1.1352x; 1.1124x over previous
//
#include <hip/hip_runtime.h>

typedef unsigned short u16;
typedef float floatx4 __attribute__((ext_vector_type(4)));
typedef short shortx8 __attribute__((ext_vector_type(8)));

#define DIN 2048

__device__ __forceinline__ u16 f2bf(float f){
  unsigned u = __float_as_uint(f);
  u = (u + 0x7fffu + ((u>>16)&1u))>>16;
  return (u16)u;
}
__device__ __forceinline__ float sigf(float x){ return 1.f/(1.f+__expf(-x)); }
__device__ __forceinline__ float siluf(float x){ return x*sigf(x); }

// ---------------- workspace layout (bytes) ----------------
#define OFF_WINP  0ull            // 4096x1024 bf16
#define OFF_WG1   8388608ull      // 1024x2048 bf16
#define OFF_WG2   12582912ull     // 2048x1024 bf16
#define OFF_WOP   16777216ull     // 1024x2048 bf16
#define OFF_XB    20971520ull     // 1024x1024 bf16
#define OFF_XIN   23068672ull     // 1024x2048 f32 (xin -> Hinit -> t1acc0)
#define OFF_SGATE 31457280ull     // 1024x2048 f32 silu(gate)
#define OFF_X1    39845888ull     // 512x2048 f32  (x1 -> t1acc1)
#define OFF_X2    44040192ull     // 256x2048 f32
#define OFF_XC0   46137344ull     // 1024x2048 f32 (first 4MB -> ctxb bf16; second 4MB -> ypacc1)
#define OFF_XC1   54525952ull     // 512x2048 f32  (xc1 -> t1b bf16)
#define OFF_XC2   58720256ull     // 256x2048 f32
#define OFF_FUSED 60817408ull     // 1024x2048 f32 (pre-fuse: dt0) -> fused
#define OFF_G3O   69206016ull     // (pre-fuse: dt1 4MB + dt2 2MB) -> g3o bf16 4MB
#define OFF_Y0    75497472ull     // 1024x2048 f32 (pre-scan: PS summaries span Y0..Y2)
#define OFF_Y1    83886080ull     // 512x2048 f32  (y1 -> ypacc0)
#define OFF_Y2    88080384ull     // 256x2048 f32
#define OFF_P0    90177536ull     // 1024x32 f32
#define OFF_P1    90308608ull     // 512x32 f32
#define OFF_P2    90374144ull     // 256x32 f32  (end 90406912 ~ 86.2 MiB)
// aliases
#define OFF_CTXB  OFF_XC0
#define OFF_T1B   OFF_XC1
#define OFF_PS    OFF_Y0
#define OFF_HINIT OFF_XIN
#define OFF_T1A0  OFF_XIN
#define OFF_T1A1  OFF_X1
#define OFF_YPA0  OFF_Y1
#define OFF_YPA1  (OFF_XC0 + 4194304ull)
#define OFF_DT0   OFF_FUSED                  // 8 MB (dead until fuse_kernel)
#define OFF_DT1   OFF_G3O                    // 4 MB (dead until G3)
#define OFF_DT2   (OFF_G3O + 4194304ull)     // 2 MB (ends exactly at Y0)

__device__ __forceinline__ void gld_lds16(const void* g, void* l){
  __builtin_amdgcn_global_load_lds((const __attribute__((address_space(1))) unsigned*)g,
                                   (__attribute__((address_space(3))) unsigned*)l, 16, 0, 0);
}

// ---------------- f32 -> bf16 conversion (5 segments, 4 elems/thread) ----------------
__global__ __launch_bounds__(256) void cvt_kernel(
    const float* __restrict__ s0, u16* __restrict__ d0,
    const float* __restrict__ s1, u16* __restrict__ d1,
    const float* __restrict__ s2, u16* __restrict__ d2,
    const float* __restrict__ s3, u16* __restrict__ d3,
    const float* __restrict__ s4, u16* __restrict__ d4)
{
  int i = (blockIdx.x*256 + threadIdx.x)*4;
  const float* s; u16* d;
  if      (i <  4194304){ s=s0; d=d0; }
  else if (i <  6291456){ s=s1; d=d1; i -=  4194304; }
  else if (i <  8388608){ s=s2; d=d2; i -=  6291456; }
  else if (i < 10485760){ s=s3; d=d3; i -=  8388608; }
  else                  { s=s4; d=d4; i -= 10485760; }
  const float4 v = *(const float4*)(s + i);
  ushort4 o; o.x = f2bf(v.x); o.y = f2bf(v.y); o.z = f2bf(v.z); o.w = f2bf(v.w);
  *(ushort4*)(d + i) = o;
}

// ---------------- MFMA bt-GEMM (R5/R7-vetted inner loop): BK=32, dbuf ----------
template<int MODE, int BM>
__global__ __launch_bounds__(256) void gemm_bt(
    const u16* __restrict__ A, const u16* __restrict__ B,
    int N, int K, int Ks,
    float* __restrict__ out_f, float* __restrict__ out_f2, u16* __restrict__ out_b,
    const float* __restrict__ ex0f, const float* __restrict__ ex1f,
    float* __restrict__ ex0, float* __restrict__ ex1)
{
  constexpr int NI = BM/32;
  constexpr int IP = BM/64;
  __shared__ u16 smA[2][BM*32];
  __shared__ u16 smB[2][BM*32];
  const int tid  = threadIdx.x;
  const int m0   = blockIdx.y * BM;
  const int n0   = blockIdx.x * BM;
  const int wv   = tid >> 6;
  const int lane = tid & 63;
  const int mw   = (wv >> 1) * (BM/2);
  const int nw   = (wv & 1) * (BM/2);
  const int quad = lane >> 4;
  const int l16  = lane & 15;
  const int srow = tid >> 2;
  const int scol = (tid & 3) * 8;

  floatx4 acc[NI][NI];
#pragma unroll
  for (int i=0;i<NI;i++)
#pragma unroll
    for (int j=0;j<NI;j++) acc[i][j] = (floatx4)0.f;

  const int kStart = blockIdx.z * Ks;
  const int kEnd   = kStart + Ks;

  auto stage = [&](int buf, int k0){
#pragma unroll
    for (int p=0;p<IP;p++){
      gld_lds16(A + (size_t)(m0 + p*64 + srow)*K + k0 + scol, &smA[buf][p*2048 + wv*512]);
      gld_lds16(B + (size_t)(n0 + p*64 + srow)*K + k0 + scol, &smB[buf][p*2048 + wv*512]);
    }
  };

  stage(0, kStart);
  int cur = 0;
  for (int k0 = kStart; k0 < kEnd; k0 += 32) {
    __syncthreads();
    if (k0 + 32 < kEnd) stage(cur^1, k0+32);
    shortx8 af[NI], bfr[NI];
#pragma unroll
    for (int i=0;i<NI;i++){
      af[i]  = *(const shortx8*)&smA[cur][(mw + i*16 + l16)*32 + quad*8];
      bfr[i] = *(const shortx8*)&smB[cur][(nw + i*16 + l16)*32 + quad*8];
    }
#pragma unroll
    for (int i=0;i<NI;i++)
#pragma unroll
      for (int j=0;j<NI;j++)
        acc[i][j] = __builtin_amdgcn_mfma_f32_16x16x32_bf16(af[i], bfr[j], acc[i][j], 0, 0, 0);
    cur ^= 1;
  }

#pragma unroll
  for (int i=0;i<NI;i++){
    const int mb = m0 + mw + i*16 + quad*4;
#pragma unroll
    for (int j=0;j<NI;j++){
      const int n = n0 + nw + j*16 + l16;
      const floatx4 v4 = acc[i][j];
      if (MODE == 0){
        if (n < 2048){
#pragma unroll
          for (int r=0;r<4;r++) out_f[(size_t)(mb+r)*2048 + n] = v4[r];
          ex0[(size_t)(mb>>1)*2048 + n]       = 0.5f*(v4[0]+v4[1]);
          ex0[(size_t)((mb>>1)+1)*2048 + n]   = 0.5f*(v4[2]+v4[3]);
          ex1[(size_t)(mb>>2)*2048 + n]       = 0.25f*(v4[0]+v4[1]+v4[2]+v4[3]);
        } else {
#pragma unroll
          for (int r=0;r<4;r++) out_f2[(size_t)(mb+r)*2048 + (n-2048)] = siluf(v4[r]);
        }
      } else if (MODE == 2){
#pragma unroll
        for (int r=0;r<4;r++){
          const size_t idx = (size_t)(mb+r)*N + n;
          out_b[idx] = f2bf(sigf(v4[r]) * ex0f[idx] * ex1f[idx]);
        }
      } else {
        float* dst = blockIdx.z ? out_f2 : out_f;
#pragma unroll
        for (int r=0;r<4;r++) dst[(size_t)(mb+r)*N + n] = v4[r];
      }
    }
  }
}

// ---------------- G2 combine: t1 = silu(acc0+acc1) -> bf16 ----------------
__global__ __launch_bounds__(256) void g2_epi(const float* __restrict__ a,
    const float* __restrict__ b, u16* __restrict__ o){
  const int i = (blockIdx.x*256 + threadIdx.x)*4;
  const float4 va = *(const float4*)(a+i);
  const float4 vb = *(const float4*)(b+i);
  ushort4 r;
  r.x = f2bf(siluf(va.x+vb.x)); r.y = f2bf(siluf(va.y+vb.y));
  r.z = f2bf(siluf(va.z+vb.z)); r.w = f2bf(siluf(va.w+vb.w));
  *(ushort4*)(o+i) = r;
}

// ---------------- causal depthwise conv (K=4) + silu, all scales ----------------
__global__ __launch_bounds__(256) void conv_kernel(const float* __restrict__ xin,
    const float* __restrict__ x1, const float* __restrict__ x2,
    const float* __restrict__ cw, const float* __restrict__ cb,
    float* __restrict__ xc0, float* __restrict__ xc1, float* __restrict__ xc2){
  const int idx = blockIdx.x*256 + threadIdx.x;
  const float* xs; float* xc; int s, local;
  if (idx < 1024*DIN)              { s=0; local=idx;             xs=xin; xc=xc0; }
  else if (idx < (1024+512)*DIN)   { s=1; local=idx-1024*DIN;    xs=x1;  xc=xc1; }
  else                             { s=2; local=idx-1536*DIN;    xs=x2;  xc=xc2; }
  const int t = local >> 11, d = local & 2047;
  const float* w = cw + ((size_t)(s*DIN) + d)*4;
  float acc = cb[s*DIN + d];
#pragma unroll
  for (int j=0;j<4;j++){
    const int tt = t - 3 + j;
    if (tt >= 0) acc += w[j] * xs[(size_t)tt*DIN + d];
  }
  xc[local] = siluf(acc);
}

// ---------------- xproj: block per t, xc row staged in LDS ----------------
__global__ __launch_bounds__(256) void xproj_kernel(const float* __restrict__ xc0,
    const float* __restrict__ xc1, const float* __restrict__ xc2,
    const float* __restrict__ xw,
    float* __restrict__ p0, float* __restrict__ p1, float* __restrict__ p2){
  __shared__ float srow[DIN];
  const int b = blockIdx.x;
  const float* xc; float* proj; int s, t;
  if (b < 1024)      { s=0; t=b;       xc=xc0; proj=p0; }
  else if (b < 1536) { s=1; t=b-1024;  xc=xc1; proj=p1; }
  else               { s=2; t=b-1536;  xc=xc2; proj=p2; }
  const float* xr = xc + (size_t)t*DIN;
  const int tid = threadIdx.x;
#pragma unroll
  for (int q=0;q<2;q++){
    const int k = (q*256 + tid)*4;
    *(float4*)&srow[k] = *(const float4*)&xr[k];
  }
  __syncthreads();
  const int i = tid >> 3;
  const int j = tid & 7;
  const float* w = xw + ((size_t)s*32 + i)*DIN;
  float acc = 0.f;
#pragma unroll 8
  for (int c=0;c<256;c++){
    const int k = j + 8*c;
    acc += srow[k]*w[k];
  }
  acc += __shfl_xor(acc,1); acc += __shfl_xor(acc,2); acc += __shfl_xor(acc,4);
  if (j == 0) proj[t*32 + i] = acc;
}

// ---------------- chunked scan, phase 1 ----------------
// one thread per channel, 16 states. 128-thread blocks: s0 512, s1 256, s2 128 = 896.
// dt = softplus(softplus(z)) = log(2+e^z)  [exact closed form];  exp(-dt) = 1/(2+e^z).
__global__ __launch_bounds__(128) void scan_p1(
    const float* __restrict__ xc0, const float* __restrict__ xc1, const float* __restrict__ xc2,
    const float* __restrict__ p0,  const float* __restrict__ p1,  const float* __restrict__ p2,
    const float* __restrict__ dtw, const float* __restrict__ dtb,
    float* __restrict__ dt0, float* __restrict__ dt1, float* __restrict__ dt2,
    float2* __restrict__ PS)
{
  __shared__ float sproj[32*32];
  int b = blockIdx.x;
  const float *xc, *proj; float* dto; int base, s;
  if (b < 512)      { xc=xc0; proj=p0; dto=dt0; base=0;  s=0; }
  else if (b < 768) { b-=512; xc=xc1; proj=p1; dto=dt1; base=32; s=1; }
  else              { b-=768; xc=xc2; proj=p2; dto=dt2; base=48; s=2; }
  const int chunk = b >> 4;
  const int tid   = threadIdx.x;
  const int d     = (b & 15)*128 + tid;
  const int t0    = chunk*32;
  {
    const int k = tid*8;
    *(float4*)&sproj[k]   = *(const float4*)&proj[t0*32 + k];
    *(float4*)&sproj[k+4] = *(const float4*)&proj[t0*32 + k + 4];
  }
  __syncthreads();

  float wreg[16];
  const float* wr = dtw + ((size_t)(s*DIN) + d)*16;
#pragma unroll
  for (int n=0;n<16;n++) wreg[n] = wr[n];
  const float bias = dtb[s*DIN + d];

  float H[16];
#pragma unroll
  for (int n=0;n<16;n++) H[n] = 0.f;
  float S = 0.f;
  const float* xcp = xc + (size_t)t0*DIN + d;
  float* dtp = dto + (size_t)t0*DIN + d;
  for (int tt=0; tt<32; tt++){
    const float xcv = xcp[(size_t)tt*DIN];
    const float* Bp = &sproj[tt*32];
    float z = bias;
#pragma unroll
    for (int n=0;n<16;n++) z += Bp[n]*wreg[n];
    z = fminf(z, 60.f);
    const float E     = __expf(z);
    const float denom = 2.f + E;
    const float e     = __builtin_amdgcn_rcpf(denom);   // exp(-dt)
    const float dtv   = __logf(denom);                  // dt
    dtp[(size_t)tt*DIN] = dtv;
    S += dtv;
    const float c = dtv*xcv;
    float ep = e;
#pragma unroll
    for (int n=0;n<16;n++){
      const float dA  = fmaxf(ep, 1e-38f);
      const float dBx = fmaxf(c*Bp[n], 1e-38f);
      H[n] = dA*H[n] + dBx;
      ep *= e;
    }
  }
  // chunk product P[n] = exp(-(n+1)*S)
  const float q = __expf(-S);
  float qp = q;
  float2* o = PS + ((size_t)(base+chunk)*2048 + d)*16;
#pragma unroll
  for (int n=0;n<16;n++){ float2 v; v.x = qp; v.y = H[n]; o[n] = v; qp *= q; }
}

// ---------------- combine (56 chunk summaries) ----------------
__global__ __launch_bounds__(256) void scan_combine(const float2* __restrict__ PS,
                                                    float* __restrict__ Hinit){
  int id = blockIdx.x*256 + threadIdx.x;
  int base, C;
  if (id < 32768)      { base=0;  C=32; }
  else if (id < 65536) { id-=32768; base=32; C=16; }
  else                 { id-=65536; base=48; C=8;  }
  const size_t off = (size_t)base*32768 + id;
  const float2* ps = PS + off;
  float* hi = Hinit + off;
  float H = 0.f;
  for (int c=0;c<C;c++){
    hi[(size_t)c*32768] = H;
    const float2 v = ps[(size_t)c*32768];
    H = v.x*H + v.y;
  }
}

// ---------------- chunked scan, phase 2 (dt preloaded) ----------------
__global__ __launch_bounds__(128) void scan_p2(
    const float* __restrict__ xc0, const float* __restrict__ xc1, const float* __restrict__ xc2,
    const float* __restrict__ p0,  const float* __restrict__ p1,  const float* __restrict__ p2,
    const float* __restrict__ dt0, const float* __restrict__ dt1, const float* __restrict__ dt2,
    const float* __restrict__ Hinit, const float* __restrict__ Dp_all,
    float* __restrict__ y0, float* __restrict__ y1, float* __restrict__ y2)
{
  __shared__ float sproj[32*32];
  int b = blockIdx.x;
  const float *xc, *proj, *dti; float* y; int base, s;
  if (b < 512)      { xc=xc0; proj=p0; dti=dt0; y=y0; base=0;  s=0; }
  else if (b < 768) { b-=512; xc=xc1; proj=p1; dti=dt1; y=y1; base=32; s=1; }
  else              { b-=768; xc=xc2; proj=p2; dti=dt2; y=y2; base=48; s=2; }
  const int chunk = b >> 4;
  const int tid   = threadIdx.x;
  const int d     = (b & 15)*128 + tid;
  const int t0    = chunk*32;
  {
    const int k = tid*8;
    *(float4*)&sproj[k]   = *(const float4*)&proj[t0*32 + k];
    *(float4*)&sproj[k+4] = *(const float4*)&proj[t0*32 + k + 4];
  }
  __syncthreads();

  float H[16];
  const float* hi = Hinit + ((size_t)(base+chunk)*2048 + d)*16;
#pragma unroll
  for (int n=0;n<16;n++) H[n] = hi[n];
  const float Dv = Dp_all[s*DIN + d];
  const float* xcp = xc + (size_t)t0*DIN + d;
  const float* dtp = dti + (size_t)t0*DIN + d;
  float* yp = y + (size_t)t0*DIN + d;
  for (int tt=0; tt<32; tt++){
    const float xcv = xcp[(size_t)tt*DIN];
    const float dtv = dtp[(size_t)tt*DIN];
    const float* Bp = &sproj[tt*32];
    const float e = __expf(-dtv);
    const float c = dtv*xcv;
    float ep = e;
    float pacc = 0.f;
#pragma unroll
    for (int n=0;n<16;n++){
      const float dA  = fmaxf(ep, 1e-38f);
      const float dBx = fmaxf(c*Bp[n], 1e-38f);
      H[n] = dA*H[n] + dBx;
      pacc += Bp[16+n]*H[n];
      ep *= e;
    }
    yp[(size_t)tt*DIN] = pacc + Dv*xcv;
  }
}

// ---------------- upsample + fuse + ctx ----------------
__device__ __forceinline__ float ups_read(const float* __restrict__ ys, int Tin, int t, int d){
  const float scale = (float)Tin * (1.f/1024.f);
  float pos = ((float)t + 0.5f)*scale - 0.5f;
  pos = fminf(fmaxf(pos, 0.f), (float)(Tin-1));
  const int lo = (int)floorf(pos);
  const float w = pos - (float)lo;
  const int hi = min(lo+1, Tin-1);
  return ys[(size_t)lo*DIN + d]*(1.f-w) + ys[(size_t)hi*DIN + d]*w;
}

__global__ __launch_bounds__(256) void fuse_kernel(const float* __restrict__ y0,
    const float* __restrict__ y1, const float* __restrict__ y2,
    const float* __restrict__ sw, u16* __restrict__ ctxb, float* __restrict__ fused){
  const int idx = blockIdx.x*256 + threadIdx.x;
  const int t = idx >> 11, d = idx & 2047;
  const float w0r = sw[0], w1r = sw[1], w2r = sw[2];
  const float mx = fmaxf(w0r, fmaxf(w1r, w2r));
  float e0 = __expf(w0r-mx), e1 = __expf(w1r-mx), e2 = __expf(w2r-mx);
  const float inv = 1.f/(e0+e1+e2);
  e0 *= inv; e1 *= inv; e2 *= inv;
  const float o0 = y0[idx];
  const float o1 = ups_read(y1, 512, t, d);
  const float o2 = ups_read(y2, 256, t, d);
  fused[idx] = e0*o0 + e1*o1 + e2*o2;
  ctxb[idx]  = f2bf((o0+o1+o2)*(1.f/3.f));
}

// ---------------- LayerNorm (reads split-K partials + residual) ----------------
__global__ __launch_bounds__(256) void ln_kernel(const float* __restrict__ ya,
    const float* __restrict__ yb, const float* __restrict__ xr,
    const float* __restrict__ g, const float* __restrict__ b, float* __restrict__ out){
  __shared__ float red[4];
  const int t = blockIdx.x;
  const size_t ro = (size_t)t*1024;
  float v[4];
  float s = 0.f;
#pragma unroll
  for (int i=0;i<4;i++){
    const int c = threadIdx.x + i*256;
    v[i] = ya[ro+c] + yb[ro+c] + xr[ro+c];
    s += v[i];
  }
  s += __shfl_xor(s,1); s += __shfl_xor(s,2); s += __shfl_xor(s,4);
  s += __shfl_xor(s,8); s += __shfl_xor(s,16); s += __shfl_xor(s,32);
  if ((threadIdx.x & 63) == 0) red[threadIdx.x>>6] = s;
  __syncthreads();
  const float mu = (red[0]+red[1]+red[2]+red[3]) * (1.f/1024.f);
  __syncthreads();
  float q = 0.f;
#pragma unroll
  for (int i=0;i<4;i++){ const float dd = v[i]-mu; q += dd*dd; }
  q += __shfl_xor(q,1); q += __shfl_xor(q,2); q += __shfl_xor(q,4);
  q += __shfl_xor(q,8); q += __shfl_xor(q,16); q += __shfl_xor(q,32);
  if ((threadIdx.x & 63) == 0) red[threadIdx.x>>6] = q;
  __syncthreads();
  const float rstd = rsqrtf((red[0]+red[1]+red[2]+red[3]) * (1.f/1024.f) + 1e-5f);
#pragma unroll
  for (int i=0;i<4;i++){
    const int c = threadIdx.x + i*256;
    out[ro + c] = (v[i]-mu)*rstd*g[c] + b[c];
  }
}

extern "C" void kernel_launch(void* const* d_in, const int* in_sizes, int n_in,
                              void* d_out, int out_size, void* d_ws, size_t ws_size,
                              hipStream_t stream) {
  const float* x     = (const float*)d_in[0];
  const float* inpw  = (const float*)d_in[1];
  const float* convw = (const float*)d_in[2];
  const float* convb = (const float*)d_in[3];
  const float* xpw   = (const float*)d_in[4];
  const float* dtw   = (const float*)d_in[5];
  const float* dtb   = (const float*)d_in[6];
  const float* Dp    = (const float*)d_in[7];
  const float* sw    = (const float*)d_in[8];
  const float* gw1   = (const float*)d_in[9];
  const float* gw2   = (const float*)d_in[10];
  const float* opw   = (const float*)d_in[11];
  const float* lng   = (const float*)d_in[12];
  const float* lnb   = (const float*)d_in[13];
  float* out = (float*)d_out;

  char* ws = (char*)d_ws;
  u16*    wInp  = (u16*)   (ws + OFF_WINP);
  u16*    wG1   = (u16*)   (ws + OFF_WG1);
  u16*    wG2   = (u16*)   (ws + OFF_WG2);
  u16*    wOp   = (u16*)   (ws + OFF_WOP);
  u16*    xb    = (u16*)   (ws + OFF_XB);
  float*  xin   = (float*) (ws + OFF_XIN);
  float*  sgate = (float*) (ws + OFF_SGATE);
  float*  x1    = (float*) (ws + OFF_X1);
  float*  x2    = (float*) (ws + OFF_X2);
  float*  xc0   = (float*) (ws + OFF_XC0);
  float*  xc1   = (float*) (ws + OFF_XC1);
  float*  xc2   = (float*) (ws + OFF_XC2);
  float*  dt0   = (float*) (ws + OFF_DT0);
  float*  dt1   = (float*) (ws + OFF_DT1);
  float*  dt2   = (float*) (ws + OFF_DT2);
  float*  y0    = (float*) (ws + OFF_Y0);
  float*  y1    = (float*) (ws + OFF_Y1);
  float*  y2    = (float*) (ws + OFF_Y2);
  float*  p0    = (float*) (ws + OFF_P0);
  float*  p1    = (float*) (ws + OFF_P1);
  float*  p2    = (float*) (ws + OFF_P2);
  float2* PS    = (float2*)(ws + OFF_PS);
  float*  Hinit = (float*) (ws + OFF_HINIT);
  u16*    ctxb  = (u16*)   (ws + OFF_CTXB);
  u16*    t1b   = (u16*)   (ws + OFF_T1B);
  float*  fused = (float*) (ws + OFF_FUSED);
  u16*    g3o   = (u16*)   (ws + OFF_G3O);
  float*  t1a0  = (float*) (ws + OFF_T1A0);
  float*  t1a1  = (float*) (ws + OFF_T1A1);
  float*  ypa0  = (float*) (ws + OFF_YPA0);
  float*  ypa1  = (float*) (ws + OFF_YPA1);

  // convert f32 -> bf16: big GEMM weights + x
  cvt_kernel<<<11264, 256, 0, stream>>>(inpw, wInp, gw1, wG1, gw2, wG2, opw, wOp, x, xb);
  // G1: xz = x @ in_proj_w^T -> x_in (f32) + downsampled x1,x2 + silu(gate)  [1024 blocks]
  gemm_bt<0,64><<<dim3(64, 16, 1), 256, 0, stream>>>(xb, wInp, 4096, 1024, 1024,
                                                     xin, sgate, nullptr, nullptr, nullptr, x1, x2);
  // conv + silu (all scales)
  conv_kernel<<<(1792*DIN)/256, 256, 0, stream>>>(xin, x1, x2, convw, convb, xc0, xc1, xc2);
  // xproj (block per t, LDS-staged xc row)
  xproj_kernel<<<1792, 256, 0, stream>>>(xc0, xc1, xc2, xpw, p0, p1, p2);
  // chunked SSM scan (closed-form dt; dt computed in p1, reused in p2)
  scan_p1<<<896, 128, 0, stream>>>(xc0, xc1, xc2, p0, p1, p2, dtw, dtb,
                                   dt0, dt1, dt2, PS);
  scan_combine<<<384, 256, 0, stream>>>(PS, Hinit);
  scan_p2<<<896, 128, 0, stream>>>(xc0, xc1, xc2, p0, p1, p2, dt0, dt1, dt2,
                                   Hinit, Dp, y0, y1, y2);
  // upsample + fuse + ctx  (fused overwrites dt0 — dead; ctxb over xc0)
  fuse_kernel<<<(1024*DIN)/256, 256, 0, stream>>>(y0, y1, y2, sw, ctxb, fused);
  // G2: ctx @ gate_w1^T  split-K=2 -> partials  [512 blocks]
  gemm_bt<4,64><<<dim3(16, 16, 2), 256, 0, stream>>>(ctxb, wG1, 1024, 2048, 1024,
                                                     t1a0, t1a1, nullptr, nullptr, nullptr, nullptr, nullptr);
  g2_epi<<<1024, 256, 0, stream>>>(t1a0, t1a1, t1b);
  // G3: g3o = sigmoid(t1 @ gate_w2^T) * fused * sgate  [512 blocks; g3o over dt1 — dead]
  gemm_bt<2,64><<<dim3(32, 16, 1), 256, 0, stream>>>(t1b, wG2, 2048, 1024, 1024,
                                                     nullptr, nullptr, g3o, fused, sgate, nullptr, nullptr);
  // G4: g3o @ out_proj_w^T  split-K=2 -> partials  [512 blocks]
  gemm_bt<4,64><<<dim3(16, 16, 2), 256, 0, stream>>>(g3o, wOp, 1024, 2048, 1024,
                                                     ypa0, ypa1, nullptr, nullptr, nullptr, nullptr, nullptr);
  // LayerNorm (sums partials + residual) -> f32 out
  ln_kernel<<<1024, 256, 0, stream>>>(ypa0, ypa1, x, lng, lnb, out);
}

// Round 10
// 299.530 us; speedup vs baseline: 1.1479x; 1.0112x over previous
//
#include <hip/hip_runtime.h>

typedef unsigned short u16;
typedef float floatx2 __attribute__((ext_vector_type(2)));
typedef float floatx4 __attribute__((ext_vector_type(4)));
typedef short shortx8 __attribute__((ext_vector_type(8)));

#define DIN 2048

__device__ __forceinline__ u16 f2bf(float f){
  unsigned u = __float_as_uint(f);
  u = (u + 0x7fffu + ((u>>16)&1u))>>16;
  return (u16)u;
}
__device__ __forceinline__ float sigf(float x){ return 1.f/(1.f+__expf(-x)); }
__device__ __forceinline__ float siluf(float x){ return x*sigf(x); }
__device__ __forceinline__ floatx2 max2(floatx2 a, floatx2 b){
  floatx2 r; r.x = fmaxf(a.x, b.x); r.y = fmaxf(a.y, b.y); return r;
}

// ---------------- workspace layout (bytes) ----------------
#define OFF_WINP  0ull            // 4096x1024 bf16
#define OFF_WG1   8388608ull      // 1024x2048 bf16
#define OFF_WG2   12582912ull     // 2048x1024 bf16
#define OFF_WOP   16777216ull     // 1024x2048 bf16
#define OFF_XB    20971520ull     // 1024x1024 bf16
#define OFF_XIN   23068672ull     // 1024x2048 f32 (xin -> t1acc0)
#define OFF_SGATE 31457280ull     // 1024x2048 f32 silu(gate)
#define OFF_X1    39845888ull     // 512x2048 f32  (x1 -> t1acc1)
#define OFF_X2    44040192ull     // 256x2048 f32
#define OFF_XC0   46137344ull     // 1024x2048 f32 (first 4MB -> ctxb bf16; second 4MB -> ypacc1)
#define OFF_XC1   54525952ull     // 512x2048 f32  (xc1 -> t1b bf16)
#define OFF_XC2   58720256ull     // 256x2048 f32
#define OFF_FUSED 60817408ull     // 1024x2048 f32 (pre-fuse: dt0) -> fused
#define OFF_G3O   69206016ull     // (pre-fuse: dt1 4MB + dt2 2MB) -> g3o bf16 4MB
#define OFF_Y0    75497472ull     // 1024x2048 f32 (y0 -> ...)
#define OFF_Y1    83886080ull     // 512x2048 f32  (y1 -> ypacc0)
#define OFF_Y2    88080384ull     // 256x2048 f32
#define OFF_P0    90177536ull     // 1024x32 f32
#define OFF_P1    90308608ull     // 512x32 f32
#define OFF_P2    90374144ull     // 256x32 f32  (end 90406912)
// new high region (ws is ~256 MiB; observed via harness 268MB poison fill)
#define OFF_PS    92274688ull     // 112 rows x 2048 x 16 x float2 = 29,360,128 B
#define OFF_HINIT 121634816ull    // 112 x 2048 x 16 x f32      = 14,680,064 B (end ~130 MiB)
// aliases
#define OFF_CTXB  OFF_XC0
#define OFF_T1B   OFF_XC1
#define OFF_T1A0  OFF_XIN
#define OFF_T1A1  OFF_X1
#define OFF_YPA0  OFF_Y1
#define OFF_YPA1  (OFF_XC0 + 4194304ull)
#define OFF_DT0   OFF_FUSED                  // 8 MB (dead until fuse_kernel)
#define OFF_DT1   OFF_G3O                    // 4 MB (dead until G3)
#define OFF_DT2   (OFF_G3O + 4194304ull)     // 2 MB (ends exactly at Y0)

__device__ __forceinline__ void gld_lds16(const void* g, void* l){
  __builtin_amdgcn_global_load_lds((const __attribute__((address_space(1))) unsigned*)g,
                                   (__attribute__((address_space(3))) unsigned*)l, 16, 0, 0);
}

// ---------------- f32 -> bf16 conversion (5 segments, 4 elems/thread) ----------------
__global__ __launch_bounds__(256) void cvt_kernel(
    const float* __restrict__ s0, u16* __restrict__ d0,
    const float* __restrict__ s1, u16* __restrict__ d1,
    const float* __restrict__ s2, u16* __restrict__ d2,
    const float* __restrict__ s3, u16* __restrict__ d3,
    const float* __restrict__ s4, u16* __restrict__ d4)
{
  int i = (blockIdx.x*256 + threadIdx.x)*4;
  const float* s; u16* d;
  if      (i <  4194304){ s=s0; d=d0; }
  else if (i <  6291456){ s=s1; d=d1; i -=  4194304; }
  else if (i <  8388608){ s=s2; d=d2; i -=  6291456; }
  else if (i < 10485760){ s=s3; d=d3; i -=  8388608; }
  else                  { s=s4; d=d4; i -= 10485760; }
  const float4 v = *(const float4*)(s + i);
  ushort4 o; o.x = f2bf(v.x); o.y = f2bf(v.y); o.z = f2bf(v.z); o.w = f2bf(v.w);
  *(ushort4*)(d + i) = o;
}

// ---------------- MFMA bt-GEMM (R5/R7-vetted inner loop): BK=32, dbuf ----------
template<int MODE, int BM>
__global__ __launch_bounds__(256) void gemm_bt(
    const u16* __restrict__ A, const u16* __restrict__ B,
    int N, int K, int Ks,
    float* __restrict__ out_f, float* __restrict__ out_f2, u16* __restrict__ out_b,
    const float* __restrict__ ex0f, const float* __restrict__ ex1f,
    float* __restrict__ ex0, float* __restrict__ ex1)
{
  constexpr int NI = BM/32;
  constexpr int IP = BM/64;
  __shared__ u16 smA[2][BM*32];
  __shared__ u16 smB[2][BM*32];
  const int tid  = threadIdx.x;
  const int m0   = blockIdx.y * BM;
  const int n0   = blockIdx.x * BM;
  const int wv   = tid >> 6;
  const int lane = tid & 63;
  const int mw   = (wv >> 1) * (BM/2);
  const int nw   = (wv & 1) * (BM/2);
  const int quad = lane >> 4;
  const int l16  = lane & 15;
  const int srow = tid >> 2;
  const int scol = (tid & 3) * 8;

  floatx4 acc[NI][NI];
#pragma unroll
  for (int i=0;i<NI;i++)
#pragma unroll
    for (int j=0;j<NI;j++) acc[i][j] = (floatx4)0.f;

  const int kStart = blockIdx.z * Ks;
  const int kEnd   = kStart + Ks;

  auto stage = [&](int buf, int k0){
#pragma unroll
    for (int p=0;p<IP;p++){
      gld_lds16(A + (size_t)(m0 + p*64 + srow)*K + k0 + scol, &smA[buf][p*2048 + wv*512]);
      gld_lds16(B + (size_t)(n0 + p*64 + srow)*K + k0 + scol, &smB[buf][p*2048 + wv*512]);
    }
  };

  stage(0, kStart);
  int cur = 0;
  for (int k0 = kStart; k0 < kEnd; k0 += 32) {
    __syncthreads();
    if (k0 + 32 < kEnd) stage(cur^1, k0+32);
    shortx8 af[NI], bfr[NI];
#pragma unroll
    for (int i=0;i<NI;i++){
      af[i]  = *(const shortx8*)&smA[cur][(mw + i*16 + l16)*32 + quad*8];
      bfr[i] = *(const shortx8*)&smB[cur][(nw + i*16 + l16)*32 + quad*8];
    }
#pragma unroll
    for (int i=0;i<NI;i++)
#pragma unroll
      for (int j=0;j<NI;j++)
        acc[i][j] = __builtin_amdgcn_mfma_f32_16x16x32_bf16(af[i], bfr[j], acc[i][j], 0, 0, 0);
    cur ^= 1;
  }

#pragma unroll
  for (int i=0;i<NI;i++){
    const int mb = m0 + mw + i*16 + quad*4;
#pragma unroll
    for (int j=0;j<NI;j++){
      const int n = n0 + nw + j*16 + l16;
      const floatx4 v4 = acc[i][j];
      if (MODE == 0){
        if (n < 2048){
#pragma unroll
          for (int r=0;r<4;r++) out_f[(size_t)(mb+r)*2048 + n] = v4[r];
          ex0[(size_t)(mb>>1)*2048 + n]       = 0.5f*(v4[0]+v4[1]);
          ex0[(size_t)((mb>>1)+1)*2048 + n]   = 0.5f*(v4[2]+v4[3]);
          ex1[(size_t)(mb>>2)*2048 + n]       = 0.25f*(v4[0]+v4[1]+v4[2]+v4[3]);
        } else {
#pragma unroll
          for (int r=0;r<4;r++) out_f2[(size_t)(mb+r)*2048 + (n-2048)] = siluf(v4[r]);
        }
      } else if (MODE == 2){
#pragma unroll
        for (int r=0;r<4;r++){
          const size_t idx = (size_t)(mb+r)*N + n;
          out_b[idx] = f2bf(sigf(v4[r]) * ex0f[idx] * ex1f[idx]);
        }
      } else {
        float* dst = blockIdx.z ? out_f2 : out_f;
#pragma unroll
        for (int r=0;r<4;r++) dst[(size_t)(mb+r)*N + n] = v4[r];
      }
    }
  }
}

// ---------------- G2 combine: t1 = silu(acc0+acc1) -> bf16 ----------------
__global__ __launch_bounds__(256) void g2_epi(const float* __restrict__ a,
    const float* __restrict__ b, u16* __restrict__ o){
  const int i = (blockIdx.x*256 + threadIdx.x)*4;
  const float4 va = *(const float4*)(a+i);
  const float4 vb = *(const float4*)(b+i);
  ushort4 r;
  r.x = f2bf(siluf(va.x+vb.x)); r.y = f2bf(siluf(va.y+vb.y));
  r.z = f2bf(siluf(va.z+vb.z)); r.w = f2bf(siluf(va.w+vb.w));
  *(ushort4*)(o+i) = r;
}

// ---------------- causal depthwise conv (K=4) + silu, all scales ----------------
__global__ __launch_bounds__(256) void conv_kernel(const float* __restrict__ xin,
    const float* __restrict__ x1, const float* __restrict__ x2,
    const float* __restrict__ cw, const float* __restrict__ cb,
    float* __restrict__ xc0, float* __restrict__ xc1, float* __restrict__ xc2){
  const int idx = blockIdx.x*256 + threadIdx.x;
  const float* xs; float* xc; int s, local;
  if (idx < 1024*DIN)              { s=0; local=idx;             xs=xin; xc=xc0; }
  else if (idx < (1024+512)*DIN)   { s=1; local=idx-1024*DIN;    xs=x1;  xc=xc1; }
  else                             { s=2; local=idx-1536*DIN;    xs=x2;  xc=xc2; }
  const int t = local >> 11, d = local & 2047;
  const float* w = cw + ((size_t)(s*DIN) + d)*4;
  float acc = cb[s*DIN + d];
#pragma unroll
  for (int j=0;j<4;j++){
    const int tt = t - 3 + j;
    if (tt >= 0) acc += w[j] * xs[(size_t)tt*DIN + d];
  }
  xc[local] = siluf(acc);
}

// ---------------- xproj: block per t, xc row staged in LDS ----------------
__global__ __launch_bounds__(256) void xproj_kernel(const float* __restrict__ xc0,
    const float* __restrict__ xc1, const float* __restrict__ xc2,
    const float* __restrict__ xw,
    float* __restrict__ p0, float* __restrict__ p1, float* __restrict__ p2){
  __shared__ float srow[DIN];
  const int b = blockIdx.x;
  const float* xc; float* proj; int s, t;
  if (b < 1024)      { s=0; t=b;       xc=xc0; proj=p0; }
  else if (b < 1536) { s=1; t=b-1024;  xc=xc1; proj=p1; }
  else               { s=2; t=b-1536;  xc=xc2; proj=p2; }
  const float* xr = xc + (size_t)t*DIN;
  const int tid = threadIdx.x;
#pragma unroll
  for (int q=0;q<2;q++){
    const int k = (q*256 + tid)*4;
    *(float4*)&srow[k] = *(const float4*)&xr[k];
  }
  __syncthreads();
  const int i = tid >> 3;
  const int j = tid & 7;
  const float* w = xw + ((size_t)s*32 + i)*DIN;
  float acc = 0.f;
#pragma unroll 8
  for (int c=0;c<256;c++){
    const int k = j + 8*c;
    acc += srow[k]*w[k];
  }
  acc += __shfl_xor(acc,1); acc += __shfl_xor(acc,2); acc += __shfl_xor(acc,4);
  if (j == 0) proj[t*32 + i] = acc;
}

// ---------------- chunked scan, phase 1: L=16, float2-packed ----------------
// one thread per channel, 16 states. 128-thr blocks: s0 1024, s1 512, s2 256 = 1792.
// dt = softplus(softplus(z)) = log(2+e^z);  exp(-dt) = 1/(2+e^z).
__global__ __launch_bounds__(128) void scan_p1(
    const float* __restrict__ xc0, const float* __restrict__ xc1, const float* __restrict__ xc2,
    const float* __restrict__ p0,  const float* __restrict__ p1,  const float* __restrict__ p2,
    const float* __restrict__ dtw, const float* __restrict__ dtb,
    float* __restrict__ dt0, float* __restrict__ dt1, float* __restrict__ dt2,
    float2* __restrict__ PS)
{
  __shared__ float sproj[16*32];
  int b = blockIdx.x;
  const float *xc, *proj; float* dto; int base, s;
  if (b < 1024)      { xc=xc0; proj=p0; dto=dt0; base=0;  s=0; }
  else if (b < 1536) { b-=1024; xc=xc1; proj=p1; dto=dt1; base=64; s=1; }
  else               { b-=1536; xc=xc2; proj=p2; dto=dt2; base=96; s=2; }
  const int chunk = b >> 4;
  const int tid   = threadIdx.x;
  const int d     = (b & 15)*128 + tid;
  const int t0    = chunk*16;
  {
    const int k = tid*4;
    *(float4*)&sproj[k] = *(const float4*)&proj[t0*32 + k];
  }
  __syncthreads();

  floatx2 w2[8];
  const floatx2* wr = (const floatx2*)(dtw + ((size_t)(s*DIN) + d)*16);
#pragma unroll
  for (int k=0;k<8;k++) w2[k] = wr[k];
  const float bias = dtb[s*DIN + d];
  const floatx2 eps2 = {1e-38f, 1e-38f};

  floatx2 H2[8];
#pragma unroll
  for (int k=0;k<8;k++) H2[k] = (floatx2)0.f;
  float S = 0.f;
  const float* xcp = xc + (size_t)t0*DIN + d;
  float* dtp = dto + (size_t)t0*DIN + d;
  for (int tt=0; tt<16; tt++){
    const float xcv = xcp[(size_t)tt*DIN];
    const floatx2* Bp2 = (const floatx2*)&sproj[tt*32];
    floatx2 zz = (floatx2)0.f;
#pragma unroll
    for (int k=0;k<8;k++) zz += Bp2[k]*w2[k];
    float z = fminf(zz.x + zz.y + bias, 60.f);
    const float E     = __expf(z);
    const float denom = 2.f + E;
    const float e     = __builtin_amdgcn_rcpf(denom);   // exp(-dt)
    const float dtv   = __logf(denom);                  // dt
    dtp[(size_t)tt*DIN] = dtv;
    S += dtv;
    const floatx2 c2  = {dtv*xcv, dtv*xcv};
    const floatx2 es  = {e*e, e*e};
    floatx2 ep2 = {e, e*e};
#pragma unroll
    for (int k=0;k<8;k++){
      const floatx2 dA  = max2(ep2, eps2);
      const floatx2 dBx = max2(c2*Bp2[k], eps2);
      H2[k] = dA*H2[k] + dBx;
      ep2 *= es;
    }
  }
  // chunk product P[n] = exp(-(n+1)*S)
  const float q = __expf(-S);
  const floatx2 qs = {q*q, q*q};
  floatx2 qp2 = {q, q*q};
  float2* o = PS + ((size_t)(base+chunk)*2048 + d)*16;
#pragma unroll
  for (int k=0;k<8;k++){
    float2 v0; v0.x = qp2.x; v0.y = H2[k].x; o[2*k]   = v0;
    float2 v1; v1.x = qp2.y; v1.y = H2[k].y; o[2*k+1] = v1;
    qp2 *= qs;
  }
}

// ---------------- combine (112 chunk rows; C=64/32/16) ----------------
__global__ __launch_bounds__(256) void scan_combine(const float2* __restrict__ PS,
                                                    float* __restrict__ Hinit){
  int id = blockIdx.x*256 + threadIdx.x;
  int base, C;
  if (id < 32768)      { base=0;  C=64; }
  else if (id < 65536) { id-=32768; base=64; C=32; }
  else                 { id-=65536; base=96; C=16; }
  const size_t off = (size_t)base*32768 + id;
  const float2* ps = PS + off;
  float* hi = Hinit + off;
  float H = 0.f;
  for (int c=0;c<C;c++){
    hi[(size_t)c*32768] = H;
    const float2 v = ps[(size_t)c*32768];
    H = v.x*H + v.y;
  }
}

// ---------------- chunked scan, phase 2: L=16, float2-packed, dt preloaded ---------
__global__ __launch_bounds__(128) void scan_p2(
    const float* __restrict__ xc0, const float* __restrict__ xc1, const float* __restrict__ xc2,
    const float* __restrict__ p0,  const float* __restrict__ p1,  const float* __restrict__ p2,
    const float* __restrict__ dt0, const float* __restrict__ dt1, const float* __restrict__ dt2,
    const float* __restrict__ Hinit, const float* __restrict__ Dp_all,
    float* __restrict__ y0, float* __restrict__ y1, float* __restrict__ y2)
{
  __shared__ float sproj[16*32];
  int b = blockIdx.x;
  const float *xc, *proj, *dti; float* y; int base, s;
  if (b < 1024)      { xc=xc0; proj=p0; dti=dt0; y=y0; base=0;  s=0; }
  else if (b < 1536) { b-=1024; xc=xc1; proj=p1; dti=dt1; y=y1; base=64; s=1; }
  else               { b-=1536; xc=xc2; proj=p2; dti=dt2; y=y2; base=96; s=2; }
  const int chunk = b >> 4;
  const int tid   = threadIdx.x;
  const int d     = (b & 15)*128 + tid;
  const int t0    = chunk*16;
  {
    const int k = tid*4;
    *(float4*)&sproj[k] = *(const float4*)&proj[t0*32 + k];
  }
  __syncthreads();

  floatx2 H2[8];
  const floatx2* hi = (const floatx2*)(Hinit + ((size_t)(base+chunk)*2048 + d)*16);
#pragma unroll
  for (int k=0;k<8;k++) H2[k] = hi[k];
  const float Dv = Dp_all[s*DIN + d];
  const floatx2 eps2 = {1e-38f, 1e-38f};
  const float* xcp = xc + (size_t)t0*DIN + d;
  const float* dtp = dti + (size_t)t0*DIN + d;
  float* yp = y + (size_t)t0*DIN + d;
  for (int tt=0; tt<16; tt++){
    const float xcv = xcp[(size_t)tt*DIN];
    const float dtv = dtp[(size_t)tt*DIN];
    const floatx2* Bp2 = (const floatx2*)&sproj[tt*32];
    const float e = __expf(-dtv);
    const floatx2 c2 = {dtv*xcv, dtv*xcv};
    const floatx2 es = {e*e, e*e};
    floatx2 ep2 = {e, e*e};
    floatx2 pacc2 = (floatx2)0.f;
#pragma unroll
    for (int k=0;k<8;k++){
      const floatx2 dA  = max2(ep2, eps2);
      const floatx2 dBx = max2(c2*Bp2[k], eps2);
      H2[k] = dA*H2[k] + dBx;
      pacc2 += Bp2[8+k]*H2[k];
      ep2 *= es;
    }
    yp[(size_t)tt*DIN] = pacc2.x + pacc2.y + Dv*xcv;
  }
}

// ---------------- upsample + fuse + ctx ----------------
__device__ __forceinline__ float ups_read(const float* __restrict__ ys, int Tin, int t, int d){
  const float scale = (float)Tin * (1.f/1024.f);
  float pos = ((float)t + 0.5f)*scale - 0.5f;
  pos = fminf(fmaxf(pos, 0.f), (float)(Tin-1));
  const int lo = (int)floorf(pos);
  const float w = pos - (float)lo;
  const int hi = min(lo+1, Tin-1);
  return ys[(size_t)lo*DIN + d]*(1.f-w) + ys[(size_t)hi*DIN + d]*w;
}

__global__ __launch_bounds__(256) void fuse_kernel(const float* __restrict__ y0,
    const float* __restrict__ y1, const float* __restrict__ y2,
    const float* __restrict__ sw, u16* __restrict__ ctxb, float* __restrict__ fused){
  const int idx = blockIdx.x*256 + threadIdx.x;
  const int t = idx >> 11, d = idx & 2047;
  const float w0r = sw[0], w1r = sw[1], w2r = sw[2];
  const float mx = fmaxf(w0r, fmaxf(w1r, w2r));
  float e0 = __expf(w0r-mx), e1 = __expf(w1r-mx), e2 = __expf(w2r-mx);
  const float inv = 1.f/(e0+e1+e2);
  e0 *= inv; e1 *= inv; e2 *= inv;
  const float o0 = y0[idx];
  const float o1 = ups_read(y1, 512, t, d);
  const float o2 = ups_read(y2, 256, t, d);
  fused[idx] = e0*o0 + e1*o1 + e2*o2;
  ctxb[idx]  = f2bf((o0+o1+o2)*(1.f/3.f));
}

// ---------------- LayerNorm (reads split-K partials + residual) ----------------
__global__ __launch_bounds__(256) void ln_kernel(const float* __restrict__ ya,
    const float* __restrict__ yb, const float* __restrict__ xr,
    const float* __restrict__ g, const float* __restrict__ b, float* __restrict__ out){
  __shared__ float red[4];
  const int t = blockIdx.x;
  const size_t ro = (size_t)t*1024;
  float v[4];
  float s = 0.f;
#pragma unroll
  for (int i=0;i<4;i++){
    const int c = threadIdx.x + i*256;
    v[i] = ya[ro+c] + yb[ro+c] + xr[ro+c];
    s += v[i];
  }
  s += __shfl_xor(s,1); s += __shfl_xor(s,2); s += __shfl_xor(s,4);
  s += __shfl_xor(s,8); s += __shfl_xor(s,16); s += __shfl_xor(s,32);
  if ((threadIdx.x & 63) == 0) red[threadIdx.x>>6] = s;
  __syncthreads();
  const float mu = (red[0]+red[1]+red[2]+red[3]) * (1.f/1024.f);
  __syncthreads();
  float q = 0.f;
#pragma unroll
  for (int i=0;i<4;i++){ const float dd = v[i]-mu; q += dd*dd; }
  q += __shfl_xor(q,1); q += __shfl_xor(q,2); q += __shfl_xor(q,4);
  q += __shfl_xor(q,8); q += __shfl_xor(q,16); q += __shfl_xor(q,32);
  if ((threadIdx.x & 63) == 0) red[threadIdx.x>>6] = q;
  __syncthreads();
  const float rstd = rsqrtf((red[0]+red[1]+red[2]+red[3]) * (1.f/1024.f) + 1e-5f);
#pragma unroll
  for (int i=0;i<4;i++){
    const int c = threadIdx.x + i*256;
    out[ro + c] = (v[i]-mu)*rstd*g[c] + b[c];
  }
}

extern "C" void kernel_launch(void* const* d_in, const int* in_sizes, int n_in,
                              void* d_out, int out_size, void* d_ws, size_t ws_size,
                              hipStream_t stream) {
  const float* x     = (const float*)d_in[0];
  const float* inpw  = (const float*)d_in[1];
  const float* convw = (const float*)d_in[2];
  const float* convb = (const float*)d_in[3];
  const float* xpw   = (const float*)d_in[4];
  const float* dtw   = (const float*)d_in[5];
  const float* dtb   = (const float*)d_in[6];
  const float* Dp    = (const float*)d_in[7];
  const float* sw    = (const float*)d_in[8];
  const float* gw1   = (const float*)d_in[9];
  const float* gw2   = (const float*)d_in[10];
  const float* opw   = (const float*)d_in[11];
  const float* lng   = (const float*)d_in[12];
  const float* lnb   = (const float*)d_in[13];
  float* out = (float*)d_out;

  char* ws = (char*)d_ws;
  u16*    wInp  = (u16*)   (ws + OFF_WINP);
  u16*    wG1   = (u16*)   (ws + OFF_WG1);
  u16*    wG2   = (u16*)   (ws + OFF_WG2);
  u16*    wOp   = (u16*)   (ws + OFF_WOP);
  u16*    xb    = (u16*)   (ws + OFF_XB);
  float*  xin   = (float*) (ws + OFF_XIN);
  float*  sgate = (float*) (ws + OFF_SGATE);
  float*  x1    = (float*) (ws + OFF_X1);
  float*  x2    = (float*) (ws + OFF_X2);
  float*  xc0   = (float*) (ws + OFF_XC0);
  float*  xc1   = (float*) (ws + OFF_XC1);
  float*  xc2   = (float*) (ws + OFF_XC2);
  float*  dt0   = (float*) (ws + OFF_DT0);
  float*  dt1   = (float*) (ws + OFF_DT1);
  float*  dt2   = (float*) (ws + OFF_DT2);
  float*  y0    = (float*) (ws + OFF_Y0);
  float*  y1    = (float*) (ws + OFF_Y1);
  float*  y2    = (float*) (ws + OFF_Y2);
  float*  p0    = (float*) (ws + OFF_P0);
  float*  p1    = (float*) (ws + OFF_P1);
  float*  p2    = (float*) (ws + OFF_P2);
  float2* PS    = (float2*)(ws + OFF_PS);
  float*  Hinit = (float*) (ws + OFF_HINIT);
  u16*    ctxb  = (u16*)   (ws + OFF_CTXB);
  u16*    t1b   = (u16*)   (ws + OFF_T1B);
  float*  fused = (float*) (ws + OFF_FUSED);
  u16*    g3o   = (u16*)   (ws + OFF_G3O);
  float*  t1a0  = (float*) (ws + OFF_T1A0);
  float*  t1a1  = (float*) (ws + OFF_T1A1);
  float*  ypa0  = (float*) (ws + OFF_YPA0);
  float*  ypa1  = (float*) (ws + OFF_YPA1);

  // convert f32 -> bf16: big GEMM weights + x
  cvt_kernel<<<11264, 256, 0, stream>>>(inpw, wInp, gw1, wG1, gw2, wG2, opw, wOp, x, xb);
  // G1: xz = x @ in_proj_w^T -> x_in (f32) + downsampled x1,x2 + silu(gate)  [1024 blocks]
  gemm_bt<0,64><<<dim3(64, 16, 1), 256, 0, stream>>>(xb, wInp, 4096, 1024, 1024,
                                                     xin, sgate, nullptr, nullptr, nullptr, x1, x2);
  // conv + silu (all scales)
  conv_kernel<<<(1792*DIN)/256, 256, 0, stream>>>(xin, x1, x2, convw, convb, xc0, xc1, xc2);
  // xproj (block per t, LDS-staged xc row)
  xproj_kernel<<<1792, 256, 0, stream>>>(xc0, xc1, xc2, xpw, p0, p1, p2);
  // chunked SSM scan (L=16, packed math; dt computed in p1, reused in p2)
  scan_p1<<<1792, 128, 0, stream>>>(xc0, xc1, xc2, p0, p1, p2, dtw, dtb,
                                    dt0, dt1, dt2, PS);
  scan_combine<<<384, 256, 0, stream>>>(PS, Hinit);
  scan_p2<<<1792, 128, 0, stream>>>(xc0, xc1, xc2, p0, p1, p2, dt0, dt1, dt2,
                                    Hinit, Dp, y0, y1, y2);
  // upsample + fuse + ctx  (fused overwrites dt0 — dead; ctxb over xc0)
  fuse_kernel<<<(1024*DIN)/256, 256, 0, stream>>>(y0, y1, y2, sw, ctxb, fused);
  // G2: ctx @ gate_w1^T  split-K=2 -> partials  [512 blocks]
  gemm_bt<4,64><<<dim3(16, 16, 2), 256, 0, stream>>>(ctxb, wG1, 1024, 2048, 1024,
                                                     t1a0, t1a1, nullptr, nullptr, nullptr, nullptr, nullptr);
  g2_epi<<<1024, 256, 0, stream>>>(t1a0, t1a1, t1b);
  // G3: g3o = sigmoid(t1 @ gate_w2^T) * fused * sgate  [512 blocks; g3o over dt1 — dead]
  gemm_bt<2,64><<<dim3(32, 16, 1), 256, 0, stream>>>(t1b, wG2, 2048, 1024, 1024,
                                                     nullptr, nullptr, g3o, fused, sgate, nullptr, nullptr);
  // G4: g3o @ out_proj_w^T  split-K=2 -> partials  [512 blocks]
  gemm_bt<4,64><<<dim3(16, 16, 2), 256, 0, stream>>>(g3o, wOp, 1024, 2048, 1024,
                                                     ypa0, ypa1, nullptr, nullptr, nullptr, nullptr, nullptr);
  // LayerNorm (sums partials + residual) -> f32 out
  ln_kernel<<<1024, 256, 0, stream>>>(ypa0, ypa1, x, lng, lnb, out);
}